// Round 1
// baseline (481.412 us; speedup 1.0000x reference)
//
#include <hip/hip_runtime.h>
#include <math.h>

#define THREADS 256

// ---------------- generic direct conv3x3, pad=1 ----------------
__global__ void k_conv3x3(const float* __restrict__ in, const float* __restrict__ w,
                          const float* __restrict__ bias, float* __restrict__ out,
                          int N, int Cin, int Cout, int H, int W, int relu) {
    int idx = blockIdx.x * THREADS + threadIdx.x;
    int total = N * Cout * H * W;
    if (idx >= total) return;
    int x = idx % W;
    int y = (idx / W) % H;
    int co = (idx / (W * H)) % Cout;
    int n = idx / (W * H * Cout);
    float acc = bias[co];
    for (int ci = 0; ci < Cin; ++ci) {
        const float* ip = in + ((size_t)(n * Cin + ci) * H) * W;
        const float* wp = w + ((size_t)(co * Cin + ci) * 9);
        #pragma unroll
        for (int ky = 0; ky < 3; ++ky) {
            int yy = y + ky - 1;
            if (yy < 0 || yy >= H) continue;
            #pragma unroll
            for (int kx = 0; kx < 3; ++kx) {
                int xx = x + kx - 1;
                if (xx < 0 || xx >= W) continue;
                acc = fmaf(ip[yy * W + xx], wp[ky * 3 + kx], acc);
            }
        }
    }
    if (relu) acc = fmaxf(acc, 0.f);
    out[idx] = acc;
}

// ---------------- 2x2 max pool, stride 2 ----------------
__global__ void k_pool(const float* __restrict__ in, float* __restrict__ out,
                       int N, int C, int Ho, int Wo) {
    int idx = blockIdx.x * THREADS + threadIdx.x;
    int total = N * C * Ho * Wo;
    if (idx >= total) return;
    int x = idx % Wo;
    int y = (idx / Wo) % Ho;
    int c = idx / (Wo * Ho);   // fused N*C
    int Wi = Wo * 2;
    const float* ip = in + ((size_t)c * (Ho * 2)) * Wi;
    float a = ip[(2 * y) * Wi + 2 * x];
    float b = ip[(2 * y) * Wi + 2 * x + 1];
    float cc = ip[(2 * y + 1) * Wi + 2 * x];
    float d = ip[(2 * y + 1) * Wi + 2 * x + 1];
    out[idx] = fmaxf(fmaxf(a, b), fmaxf(cc, d));
}

// ---------------- conv3x3 over concat(up(A), B), pad=1, relu ----------------
__global__ void k_conv3x3_catup(const float* __restrict__ A, int Ca,
                                const float* __restrict__ B, int Cb,
                                const float* __restrict__ w, const float* __restrict__ bias,
                                float* __restrict__ out, int N, int Cout, int H, int W) {
    int idx = blockIdx.x * THREADS + threadIdx.x;
    int total = N * Cout * H * W;
    if (idx >= total) return;
    int x = idx % W;
    int y = (idx / W) % H;
    int co = (idx / (W * H)) % Cout;
    int n = idx / (W * H * Cout);
    int Cin = Ca + Cb;
    int Hh = H / 2, Wh = W / 2;
    float acc = bias[co];
    for (int ci = 0; ci < Cin; ++ci) {
        const float* wp = w + ((size_t)(co * Cin + ci) * 9);
        #pragma unroll
        for (int ky = 0; ky < 3; ++ky) {
            int yy = y + ky - 1;
            if (yy < 0 || yy >= H) continue;
            #pragma unroll
            for (int kx = 0; kx < 3; ++kx) {
                int xx = x + kx - 1;
                if (xx < 0 || xx >= W) continue;
                float v;
                if (ci < Ca) {
                    v = A[((size_t)(n * Ca + ci) * Hh + (yy >> 1)) * Wh + (xx >> 1)];
                } else {
                    v = B[((size_t)(n * Cb + (ci - Ca)) * H + yy) * W + xx];
                }
                acc = fmaf(v, wp[ky * 3 + kx], acc);
            }
        }
    }
    out[idx] = fmaxf(acc, 0.f);
}

// ---------------- 1x1 conv (no relu) ----------------
__global__ void k_conv1x1(const float* __restrict__ in, const float* __restrict__ w,
                          const float* __restrict__ bias, float* __restrict__ out,
                          int N, int Cin, int Cout, int HW) {
    int idx = blockIdx.x * THREADS + threadIdx.x;
    int total = N * Cout * HW;
    if (idx >= total) return;
    int q = idx % HW;
    int co = (idx / HW) % Cout;
    int n = idx / (HW * Cout);
    float acc = bias[co];
    for (int ci = 0; ci < Cin; ++ci)
        acc = fmaf(in[((size_t)(n * Cin + ci)) * HW + q], w[co * Cin + ci], acc);
    out[idx] = acc;
}

// ---------------- embedding conv: Cin=1, Cout=100, on planes {2,3,6,7} ----------------
__global__ void k_emb(const float* __restrict__ src, const float* __restrict__ ew,
                      const float* __restrict__ eb, float* __restrict__ dst) {
    int idx = blockIdx.x * THREADS + threadIdx.x;   // 4 * 100 * 2304
    if (idx >= 4 * 100 * 2304) return;
    int q = idx % 2304;
    int e = (idx / 2304) % 100;
    int ni = idx / 230400;
    const int planes[4] = {2, 3, 6, 7};
    const float* ip = src + (size_t)planes[ni] * 2304;
    int x = q % 48, y = q / 48;
    float acc = eb[e];
    const float* wp = ew + e * 9;
    #pragma unroll
    for (int ky = 0; ky < 3; ++ky) {
        int yy = y + ky - 1;
        if (yy < 0 || yy >= 48) continue;
        #pragma unroll
        for (int kx = 0; kx < 3; ++kx) {
            int xx = x + kx - 1;
            if (xx < 0 || xx >= 48) continue;
            acc = fmaf(ip[yy * 48 + xx], wp[ky * 3 + kx], acc);
        }
    }
    dst[(size_t)ni * 230400 + (size_t)e * 2304 + q] = acc;
}

// ---------------- per-pixel squared norms of embedding ----------------
__global__ void k_norm(const float* __restrict__ e, float* __restrict__ out) {
    int idx = blockIdx.x * THREADS + threadIdx.x;  // 4 * 2304
    if (idx >= 9216) return;
    int q = idx % 2304;
    int ni = idx / 2304;
    const float* p = e + (size_t)ni * 230400 + q;
    float s = 0.f;
    for (int k = 0; k < 100; ++k) {
        float v = p[(size_t)k * 2304];
        s = fmaf(v, v, s);
    }
    out[idx] = s;
}

__global__ void k_init_inf(float* __restrict__ a, int n) {
    int idx = blockIdx.x * THREADS + threadIdx.x;
    if (idx < n) a[idx] = INFINITY;
}

// ---------------- global matching: min_p ||a_p - b_q||^2 ----------------
// grid: m(2) * n(4) * qt(18) * ps(6); block 256 = 16x16, each thread 8q x 8p regs
#define QB 128
#define PB 384
#define PCH 128
#define ECH 50

__global__ __launch_bounds__(THREADS) void k_match(
        const float* __restrict__ emb1, const float* __restrict__ emb2,
        const float* __restrict__ emb3,
        const float* __restrict__ n1, const float* __restrict__ n2,
        const float* __restrict__ n3,
        float* __restrict__ gmd, float* __restrict__ lmd) {
    int bx = blockIdx.x;
    int ps = bx % 6;
    int qt = (bx / 6) % 18;
    int n  = (bx / (6 * 18)) % 4;
    int m  = bx / (6 * 18 * 4);

    const float* ra = (m == 0 ? emb1 : emb2) + (size_t)n * 230400;
    const float* na = (m == 0 ? n1 : n2) + n * 2304;
    const float* rb = emb3 + (size_t)n * 230400;
    const float* nb = n3 + n * 2304;
    unsigned* outd = (unsigned*)((m == 0 ? gmd : lmd) + n * 2304);

    int qbase = qt * QB;
    int pbase = ps * PB;
    int tid = threadIdx.x;
    int tx = tid & 15;
    int ty = tid >> 4;

    __shared__ float a_lds[ECH][PCH];
    __shared__ float b_lds[ECH][QB];

    float nbv[8];
    #pragma unroll
    for (int j = 0; j < 8; ++j) nbv[j] = nb[qbase + ty * 8 + j];

    float dmin[8];
    #pragma unroll
    for (int j = 0; j < 8; ++j) dmin[j] = INFINITY;

    for (int pc = 0; pc < PB; pc += PCH) {
        float acc[8][8];
        #pragma unroll
        for (int i = 0; i < 8; ++i)
            #pragma unroll
            for (int j = 0; j < 8; ++j) acc[i][j] = 0.f;

        for (int ec = 0; ec < 100; ec += ECH) {
            __syncthreads();
            for (int i = tid; i < ECH * PCH; i += THREADS) {
                int e = i / PCH;
                int p = i % PCH;
                a_lds[e][p] = ra[(size_t)(ec + e) * 2304 + pbase + pc + p];
            }
            for (int i = tid; i < ECH * QB; i += THREADS) {
                int e = i / QB;
                int qq = i % QB;
                b_lds[e][qq] = rb[(size_t)(ec + e) * 2304 + qbase + qq];
            }
            __syncthreads();
            for (int e = 0; e < ECH; ++e) {
                float4 a0 = *(const float4*)&a_lds[e][tx * 8];
                float4 a1 = *(const float4*)&a_lds[e][tx * 8 + 4];
                float4 b0 = *(const float4*)&b_lds[e][ty * 8];
                float4 b1 = *(const float4*)&b_lds[e][ty * 8 + 4];
                const float av[8] = {a0.x, a0.y, a0.z, a0.w, a1.x, a1.y, a1.z, a1.w};
                const float bv[8] = {b0.x, b0.y, b0.z, b0.w, b1.x, b1.y, b1.z, b1.w};
                #pragma unroll
                for (int i = 0; i < 8; ++i)
                    #pragma unroll
                    for (int j = 0; j < 8; ++j)
                        acc[i][j] = fmaf(av[i], bv[j], acc[i][j]);
            }
        }
        #pragma unroll
        for (int i = 0; i < 8; ++i) {
            float nav = na[pbase + pc + tx * 8 + i];
            #pragma unroll
            for (int j = 0; j < 8; ++j) {
                float d2 = nav + nbv[j] - 2.f * acc[i][j];
                d2 = fmaxf(d2, 0.f);
                dmin[j] = fminf(dmin[j], d2);
            }
        }
    }
    // reduce across the 16 tx lanes (contiguous lanes within a wave)
    #pragma unroll
    for (int j = 0; j < 8; ++j) {
        float v = dmin[j];
        for (int o = 8; o > 0; o >>= 1) v = fminf(v, __shfl_xor(v, o, 64));
        dmin[j] = v;
    }
    if (tx == 0) {
        #pragma unroll
        for (int j = 0; j < 8; ++j)
            atomicMin(&outd[qbase + ty * 8 + j], __float_as_uint(dmin[j]));
    }
}

// ---------------- map dmin -> 1 - 2*sigmoid(-d) ----------------
__global__ void k_mapval(const float* __restrict__ d, float* __restrict__ v, int n) {
    int idx = blockIdx.x * THREADS + threadIdx.x;
    if (idx >= n) return;
    v[idx] = 1.f - 2.f / (1.f + expf(d[idx]));
}

// ---------------- final dsh conv over virtual concat + output select ----------------
__global__ void k_final(const float* __restrict__ x3s, const float* __restrict__ gmv,
                        const float* __restrict__ lmv, const float* __restrict__ x2,
                        const float* __restrict__ dshw, const float* __restrict__ dshb,
                        float* __restrict__ out) {
    int idx = blockIdx.x * THREADS + threadIdx.x;  // 4 * 2304
    if (idx >= 9216) return;
    int q = idx % 2304;
    int ni = idx / 2304;
    const int planes[4] = {2, 3, 6, 7};
    int n = planes[ni];
    int b = n >> 2;
    int x = q % 48, y = q / 48;
    float acc = dshb[0];
    for (int c = 0; c < 7; ++c) {
        const float* ip;
        if (c < 4) ip = x3s + (size_t)(b * 4 + c) * 2304;
        else if (c == 4) ip = gmv + (size_t)ni * 2304;
        else if (c == 5) ip = lmv + (size_t)ni * 2304;
        else ip = x2 + (size_t)n * 2304;
        const float* wp = dshw + c * 9;
        #pragma unroll
        for (int ky = 0; ky < 3; ++ky) {
            int yy = y + ky - 1;
            if (yy < 0 || yy >= 48) continue;
            #pragma unroll
            for (int kx = 0; kx < 3; ++kx) {
                int xx = x + kx - 1;
                if (xx < 0 || xx >= 48) continue;
                acc = fmaf(ip[yy * 48 + xx], wp[ky * 3 + kx], acc);
            }
        }
    }
    out[idx] = acc;
}

extern "C" void kernel_launch(void* const* d_in, const int* in_sizes, int n_in,
                              void* d_out, int out_size, void* d_ws, size_t ws_size,
                              hipStream_t stream) {
    const float* x1     = (const float*)d_in[0];
    const float* x2     = (const float*)d_in[1];
    const float* x3     = (const float*)d_in[2];
    const float* enc1_w = (const float*)d_in[3];
    const float* enc1_b = (const float*)d_in[4];
    const float* enc2_w = (const float*)d_in[5];
    const float* enc2_b = (const float*)d_in[6];
    const float* bott_w = (const float*)d_in[7];
    const float* bott_b = (const float*)d_in[8];
    const float* dec2_w = (const float*)d_in[9];
    const float* dec2_b = (const float*)d_in[10];
    const float* dec1_w = (const float*)d_in[11];
    const float* dec1_b = (const float*)d_in[12];
    const float* out_w  = (const float*)d_in[13];
    const float* out_b  = (const float*)d_in[14];
    const float* emb_w  = (const float*)d_in[15];
    const float* emb_b  = (const float*)d_in[16];
    const float* dsh_w  = (const float*)d_in[17];
    const float* dsh_b  = (const float*)d_in[18];

    float* w = (float*)d_ws;
    float* e1u  = w;                 // [2,16,48,48]  73728
    float* p1   = w + 73728;         // [2,16,24,24]  18432
    float* e2   = w + 92160;         // [2,32,24,24]  36864
    float* p2   = w + 129024;        // [2,32,12,12]  9216
    float* bt   = w + 138240;        // [2,64,12,12]  18432
    float* d2b  = w + 156672;        // [2,32,24,24]  36864
    float* d1b  = w + 193536;        // [2,16,48,48]  73728
    float* x3s  = w + 267264;        // [2,4,48,48]   18432
    float* emb1 = w + 285696;        // [4,100,2304]  921600
    float* emb2 = w + 1207296;
    float* emb3 = w + 2128896;
    float* nn1  = w + 3050496;       // [4,2304]
    float* nn2  = w + 3059712;
    float* nn3  = w + 3068928;
    float* gmd  = w + 3078144;       // [4,2304]
    float* lmd  = w + 3087360;
    float* gmv  = w + 3096576;
    float* lmv  = w + 3105792;

    // ---- UNet backbone on x3 ----
    k_conv3x3<<<dim3(288), dim3(THREADS), 0, stream>>>(x3, enc1_w, enc1_b, e1u, 2, 3, 16, 48, 48, 1);
    k_pool<<<dim3(72), dim3(THREADS), 0, stream>>>(e1u, p1, 2, 16, 24, 24);
    k_conv3x3<<<dim3(144), dim3(THREADS), 0, stream>>>(p1, enc2_w, enc2_b, e2, 2, 16, 32, 24, 24, 1);
    k_pool<<<dim3(36), dim3(THREADS), 0, stream>>>(e2, p2, 2, 32, 12, 12);
    k_conv3x3<<<dim3(72), dim3(THREADS), 0, stream>>>(p2, bott_w, bott_b, bt, 2, 32, 64, 12, 12, 1);
    k_conv3x3_catup<<<dim3(144), dim3(THREADS), 0, stream>>>(bt, 64, e2, 32, dec2_w, dec2_b, d2b, 2, 32, 24, 24);
    k_conv3x3_catup<<<dim3(288), dim3(THREADS), 0, stream>>>(d2b, 32, e1u, 16, dec1_w, dec1_b, d1b, 2, 16, 48, 48);
    k_conv1x1<<<dim3(72), dim3(THREADS), 0, stream>>>(d1b, out_w, out_b, x3s, 2, 16, 4, 2304);

    // ---- embeddings (only planes 2,3,6,7) ----
    k_emb<<<dim3(3600), dim3(THREADS), 0, stream>>>(x1, emb_w, emb_b, emb1);
    k_emb<<<dim3(3600), dim3(THREADS), 0, stream>>>(x2, emb_w, emb_b, emb2);
    k_emb<<<dim3(3600), dim3(THREADS), 0, stream>>>(x3s, emb_w, emb_b, emb3);

    // ---- norms + init ----
    k_norm<<<dim3(36), dim3(THREADS), 0, stream>>>(emb1, nn1);
    k_norm<<<dim3(36), dim3(THREADS), 0, stream>>>(emb2, nn2);
    k_norm<<<dim3(36), dim3(THREADS), 0, stream>>>(emb3, nn3);
    k_init_inf<<<dim3(72), dim3(THREADS), 0, stream>>>(gmd, 18432);  // gmd+lmd contiguous

    // ---- global matching ----
    k_match<<<dim3(864), dim3(THREADS), 0, stream>>>(emb1, emb2, emb3, nn1, nn2, nn3, gmd, lmd);

    // ---- distance -> value map ----
    k_mapval<<<dim3(72), dim3(THREADS), 0, stream>>>(gmd, gmv, 18432); // maps gmd->gmv and lmd->lmv (contiguous)

    // ---- final dsh conv + output selection ----
    k_final<<<dim3(36), dim3(THREADS), 0, stream>>>(x3s, gmv, lmv, x2, dsh_w, dsh_b, (float*)d_out);
}

// Round 2
// 285.802 us; speedup vs baseline: 1.6844x; 1.6844x over previous
//
#include <hip/hip_runtime.h>
#include <math.h>

#define THREADS 256
#define HW 2304

typedef __attribute__((ext_vector_type(8))) short short8;
typedef __attribute__((ext_vector_type(4))) float f32x4;
typedef __attribute__((ext_vector_type(8))) unsigned short us8;

typedef const __attribute__((address_space(1))) void* gas_p;
typedef __attribute__((address_space(3))) void* las_p;

__device__ __forceinline__ void gll16(const void* g, const void* l) {
    __builtin_amdgcn_global_load_lds((gas_p)g, (las_p)l, 16, 0, 0);
}

// ================= backbone =================

// enc1 conv3x3(Cin=3) + relu + write e1u, fused 2x2 maxpool -> p1
__global__ void k_enc1pool(const float* __restrict__ x3, const float* __restrict__ w,
                           const float* __restrict__ b, float* __restrict__ e1u,
                           float* __restrict__ p1) {
    int idx = blockIdx.x * THREADS + threadIdx.x;   // 2*16*24*24
    if (idx >= 18432) return;
    int px = idx % 24, py = (idx / 24) % 24, co = (idx / 576) % 16, n = idx / 9216;
    float s00 = b[co], s01 = s00, s10 = s00, s11 = s00;
    for (int ci = 0; ci < 3; ++ci) {
        const float* ip = x3 + (size_t)(n * 3 + ci) * HW;
        const float* wp = w + (co * 3 + ci) * 9;
        float pv[4][4];
        #pragma unroll
        for (int r = 0; r < 4; ++r) {
            int yy = 2 * py - 1 + r;
            #pragma unroll
            for (int c = 0; c < 4; ++c) {
                int xx = 2 * px - 1 + c;
                pv[r][c] = (yy >= 0 && yy < 48 && xx >= 0 && xx < 48) ? ip[yy * 48 + xx] : 0.f;
            }
        }
        #pragma unroll
        for (int ky = 0; ky < 3; ++ky)
            #pragma unroll
            for (int kx = 0; kx < 3; ++kx) {
                float wv = wp[ky * 3 + kx];
                s00 = fmaf(pv[ky][kx],     wv, s00);
                s01 = fmaf(pv[ky][kx + 1], wv, s01);
                s10 = fmaf(pv[ky + 1][kx], wv, s10);
                s11 = fmaf(pv[ky + 1][kx + 1], wv, s11);
            }
    }
    s00 = fmaxf(s00, 0.f); s01 = fmaxf(s01, 0.f); s10 = fmaxf(s10, 0.f); s11 = fmaxf(s11, 0.f);
    float* ob = e1u + (size_t)(n * 16 + co) * HW;
    ob[(2 * py) * 48 + 2 * px] = s00;
    ob[(2 * py) * 48 + 2 * px + 1] = s01;
    ob[(2 * py + 1) * 48 + 2 * px] = s10;
    ob[(2 * py + 1) * 48 + 2 * px + 1] = s11;
    p1[(size_t)(n * 16 + co) * 576 + py * 24 + px] = fmaxf(fmaxf(s00, s01), fmaxf(s10, s11));
}

// enc2 conv3x3(Cin=16 on 24x24) + relu -> e2, fused pool -> p2
__global__ void k_enc2pool(const float* __restrict__ p1, const float* __restrict__ w,
                           const float* __restrict__ b, float* __restrict__ e2,
                           float* __restrict__ p2) {
    int idx = blockIdx.x * THREADS + threadIdx.x;   // 2*32*12*12
    if (idx >= 9216) return;
    int px = idx % 12, py = (idx / 12) % 12, co = (idx / 144) % 32, n = idx / 4608;
    float s00 = b[co], s01 = s00, s10 = s00, s11 = s00;
    for (int ci = 0; ci < 16; ++ci) {
        const float* ip = p1 + (size_t)(n * 16 + ci) * 576;
        const float* wp = w + (co * 16 + ci) * 9;
        float pv[4][4];
        #pragma unroll
        for (int r = 0; r < 4; ++r) {
            int yy = 2 * py - 1 + r;
            #pragma unroll
            for (int c = 0; c < 4; ++c) {
                int xx = 2 * px - 1 + c;
                pv[r][c] = (yy >= 0 && yy < 24 && xx >= 0 && xx < 24) ? ip[yy * 24 + xx] : 0.f;
            }
        }
        #pragma unroll
        for (int ky = 0; ky < 3; ++ky)
            #pragma unroll
            for (int kx = 0; kx < 3; ++kx) {
                float wv = wp[ky * 3 + kx];
                s00 = fmaf(pv[ky][kx],     wv, s00);
                s01 = fmaf(pv[ky][kx + 1], wv, s01);
                s10 = fmaf(pv[ky + 1][kx], wv, s10);
                s11 = fmaf(pv[ky + 1][kx + 1], wv, s11);
            }
    }
    s00 = fmaxf(s00, 0.f); s01 = fmaxf(s01, 0.f); s10 = fmaxf(s10, 0.f); s11 = fmaxf(s11, 0.f);
    float* ob = e2 + (size_t)(n * 32 + co) * 576;
    ob[(2 * py) * 24 + 2 * px] = s00;
    ob[(2 * py) * 24 + 2 * px + 1] = s01;
    ob[(2 * py + 1) * 24 + 2 * px] = s10;
    ob[(2 * py + 1) * 24 + 2 * px + 1] = s11;
    p2[(size_t)(n * 32 + co) * 144 + py * 12 + px] = fmaxf(fmaxf(s00, s01), fmaxf(s10, s11));
}

// bottleneck conv3x3(Cin=32 on 12x12) + relu
__global__ void k_bott(const float* __restrict__ p2, const float* __restrict__ w,
                       const float* __restrict__ b, float* __restrict__ bt) {
    int idx = blockIdx.x * THREADS + threadIdx.x;   // 2*64*144
    if (idx >= 18432) return;
    int x = idx % 12, y = (idx / 12) % 12, co = (idx / 144) % 64, n = idx / 9216;
    float acc = b[co];
    for (int ci = 0; ci < 32; ++ci) {
        const float* ip = p2 + (size_t)(n * 32 + ci) * 144;
        const float* wp = w + (co * 32 + ci) * 9;
        #pragma unroll
        for (int ky = 0; ky < 3; ++ky) {
            int yy = y + ky - 1;
            if (yy < 0 || yy >= 12) continue;
            #pragma unroll
            for (int kx = 0; kx < 3; ++kx) {
                int xx = x + kx - 1;
                if (xx < 0 || xx >= 12) continue;
                acc = fmaf(ip[yy * 12 + xx], wp[ky * 3 + kx], acc);
            }
        }
    }
    bt[idx] = fmaxf(acc, 0.f);
}

// dec2: conv3x3 over concat(up(bt)[64], e2[32]) + relu
__global__ void k_dec2(const float* __restrict__ bt, const float* __restrict__ e2,
                       const float* __restrict__ w, const float* __restrict__ b,
                       float* __restrict__ d2b) {
    int idx = blockIdx.x * THREADS + threadIdx.x;   // 2*32*576
    if (idx >= 36864) return;
    int x = idx % 24, y = (idx / 24) % 24, co = (idx / 576) % 32, n = idx / 18432;
    float acc = b[co];
    for (int ci = 0; ci < 96; ++ci) {
        const float* wp = w + ((size_t)(co * 96 + ci)) * 9;
        #pragma unroll
        for (int ky = 0; ky < 3; ++ky) {
            int yy = y + ky - 1;
            if (yy < 0 || yy >= 24) continue;
            #pragma unroll
            for (int kx = 0; kx < 3; ++kx) {
                int xx = x + kx - 1;
                if (xx < 0 || xx >= 24) continue;
                float v = (ci < 64) ? bt[((size_t)(n * 64 + ci)) * 144 + (yy >> 1) * 12 + (xx >> 1)]
                                    : e2[((size_t)(n * 32 + (ci - 64))) * 576 + yy * 24 + xx];
                acc = fmaf(v, wp[ky * 3 + kx], acc);
            }
        }
    }
    d2b[idx] = fmaxf(acc, 0.f);
}

// dec1 (conv3x3 over concat(up(d2b)[32], e1u[16]) + relu) fused with out 1x1 conv -> x3s
__global__ void k_dec1out(const float* __restrict__ d2b, const float* __restrict__ e1u,
                          const float* __restrict__ w1, const float* __restrict__ b1,
                          const float* __restrict__ ow, const float* __restrict__ ob,
                          float* __restrict__ x3s) {
    int gpix = blockIdx.x * 32 + (threadIdx.x >> 3);   // 0..4607 over (n,pix)
    int cp = threadIdx.x & 7;                           // co pair
    int n = gpix / HW, pix = gpix % HW;
    int x = pix % 48, y = pix / 48;
    float a0 = b1[cp * 2], a1 = b1[cp * 2 + 1];
    for (int ci = 0; ci < 48; ++ci) {
        const float* w0 = w1 + ((size_t)(cp * 2) * 48 + ci) * 9;
        const float* wB = w1 + ((size_t)(cp * 2 + 1) * 48 + ci) * 9;
        #pragma unroll
        for (int ky = 0; ky < 3; ++ky) {
            int yy = y + ky - 1;
            if (yy < 0 || yy >= 48) continue;
            #pragma unroll
            for (int kx = 0; kx < 3; ++kx) {
                int xx = x + kx - 1;
                if (xx < 0 || xx >= 48) continue;
                float v = (ci < 32) ? d2b[((size_t)(n * 32 + ci)) * 576 + (yy >> 1) * 24 + (xx >> 1)]
                                    : e1u[((size_t)(n * 16 + (ci - 32))) * HW + yy * 48 + xx];
                a0 = fmaf(v, w0[ky * 3 + kx], a0);
                a1 = fmaf(v, wB[ky * 3 + kx], a1);
            }
        }
    }
    __shared__ float d1l[32][16];
    d1l[threadIdx.x >> 3][cp * 2] = fmaxf(a0, 0.f);
    d1l[threadIdx.x >> 3][cp * 2 + 1] = fmaxf(a1, 0.f);
    __syncthreads();
    if (threadIdx.x < 128) {
        int pl = threadIdx.x >> 2, oc = threadIdx.x & 3;
        int gp = blockIdx.x * 32 + pl;
        int n2 = gp / HW, pp = gp % HW;
        float s = ob[oc];
        #pragma unroll
        for (int ci = 0; ci < 16; ++ci) s = fmaf(d1l[pl][ci], ow[oc * 16 + ci], s);
        x3s[(size_t)(n2 * 4 + oc) * HW + pp] = s;
    }
}

// ============ embedding conv + norm + bf16 hi/lo split (+ dmin init) ============
// hl layout: [arr(3)][plane(4)][pix(2304)][256 ushort] : 128 hi bf16 (e padded) + 128 lo
__global__ __launch_bounds__(THREADS) void k_embprep(
        const float* __restrict__ x1, const float* __restrict__ x2,
        const float* __restrict__ x3s, const float* __restrict__ ew,
        const float* __restrict__ eb, unsigned short* __restrict__ hl,
        float* __restrict__ nrm, unsigned* __restrict__ initbuf) {
    int bx = blockIdx.x;
    int tid = threadIdx.x;
    if (bx >= 108) {                     // init gmd/lmd to +inf
        int i = (bx - 108) * THREADS + tid;
        if (i < 2 * 4 * HW) initbuf[i] = 0x7F800000u;
        return;
    }
    int pt = bx % 9, ni = (bx / 9) % 4, arr = bx / 36;
    int plane = 2 + (ni & 1) + 4 * (ni >> 1);        // {2,3,6,7}
    const float* src = (arr == 0 ? x1 : (arr == 1 ? x2 : x3s)) + (size_t)plane * HW;

    __shared__ float wl[1300];           // [100][12] padded weights + 100 bias
    for (int i = tid; i < 900; i += THREADS) wl[(i / 9) * 12 + (i % 9)] = ew[i];
    for (int i = tid; i < 100; i += THREADS) wl[1200 + i] = eb[i];
    __syncthreads();

    int pix = pt * THREADS + tid;
    int x = pix % 48, y = pix / 48;
    float p9[9];
    #pragma unroll
    for (int ky = 0; ky < 3; ++ky)
        #pragma unroll
        for (int kx = 0; kx < 3; ++kx) {
            int yy = y + ky - 1, xx = x + kx - 1;
            p9[ky * 3 + kx] = (yy >= 0 && yy < 48 && xx >= 0 && xx < 48) ? src[yy * 48 + xx] : 0.f;
        }

    float nsum = 0.f;
    char* rowp = (char*)(hl + (((size_t)(arr * 4 + ni)) * HW + pix) * 256);
    for (int g = 0; g < 16; ++g) {
        us8 vh, vl;
        #pragma unroll
        for (int j = 0; j < 8; ++j) {
            int e = g * 8 + j;
            float v = 0.f;
            if (e < 100) {
                v = wl[1200 + e];
                #pragma unroll
                for (int k = 0; k < 9; ++k) v = fmaf(p9[k], wl[e * 12 + k], v);
                nsum = fmaf(v, v, nsum);
            }
            unsigned bits = __float_as_uint(v);
            vh[j] = (unsigned short)(bits >> 16);
            float lo = v - __uint_as_float(bits & 0xFFFF0000u);
            vl[j] = (unsigned short)(__float_as_uint(lo) >> 16);
        }
        *(us8*)(rowp + g * 16) = vh;
        *(us8*)(rowp + 256 + g * 16) = vl;
    }
    nrm[(size_t)(arr * 4 + ni) * HW + pix] = nsum;
}

// ================= global matching via split-bf16 MFMA =================
// grid: 432 = ps(3) * qt(18) * n(4) * m(2); block 256 = 4 waves
// per block: Q-tile 128 (2 q-tiles of 16 per wave), P range 768 in 24 chunks of 32
__global__ __launch_bounds__(THREADS) void k_match(
        const unsigned short* __restrict__ hl, const float* __restrict__ nrm,
        unsigned* __restrict__ gmd, unsigned* __restrict__ lmd) {
    int bx = blockIdx.x;
    int ps = bx % 3;
    int rest = bx / 3;
    int qt = rest % 18;
    int n = (rest / 18) % 4;
    int m = rest / 72;

    const unsigned short* curhl = hl + ((size_t)(8 + n)) * HW * 256;
    const unsigned short* refhl = hl + ((size_t)(m * 4 + n)) * HW * 256;
    const float* na = nrm + (size_t)(m * 4 + n) * HW;
    const float* nb = nrm + (size_t)(8 + n) * HW;
    unsigned* outd = (m == 0 ? gmd : lmd) + (size_t)n * HW;

    int qbase = qt * 128;
    int pbase = ps * 768;

    __shared__ unsigned short lds[(128 + 32) * 256];   // cur 128 rows + ref 32 rows, 512B rows
    unsigned short* curl = lds;
    unsigned short* refl = lds + 128 * 256;

    int tid = threadIdx.x;
    int wave = tid >> 6;
    int lane = tid & 63;
    int lr = lane >> 5;       // row within pair
    int lc = lane & 31;       // 16B chunk within row

    // stage cur tile (128 rows x 512B), XOR-swizzled source so swizzled reads see linear data
    {
        const unsigned short* gb = curhl + (size_t)qbase * 256;
        for (int t = 0; t < 16; ++t) {
            int i = wave * 16 + t;          // row pair 0..63
            int r = 2 * i + lr;
            int sc = lc ^ (r & 7);
            gll16(gb + (size_t)r * 256 + sc * 8, curl + i * 512);
        }
    }
    __syncthreads();

    // preload a-frags (2 q-tiles per wave, 4 k-steps, hi+lo)
    short8 ahi[2][4], alo[2][4];
    #pragma unroll
    for (int j = 0; j < 2; ++j) {
        int r = wave * 32 + j * 16 + (lane & 15);
        #pragma unroll
        for (int ks = 0; ks < 4; ++ks) {
            int cg = ks * 4 + (lane >> 4);
            const char* p = (const char*)curl + r * 512 + ((cg ^ (r & 7)) << 4);
            ahi[j][ks] = *(const short8*)p;
            alo[j][ks] = *(const short8*)(p + 256);
        }
    }

    float dmin[2][4];
    #pragma unroll
    for (int j = 0; j < 2; ++j)
        #pragma unroll
        for (int r = 0; r < 4; ++r) dmin[j][r] = INFINITY;

    for (int pc = 0; pc < 24; ++pc) {
        __syncthreads();
        {   // stage ref chunk: 32 rows
            const unsigned short* gb = refhl + (size_t)(pbase + pc * 32) * 256;
            for (int t = 0; t < 4; ++t) {
                int i = wave * 4 + t;
                int r = 2 * i + lr;
                int sc = lc ^ (r & 7);
                gll16(gb + (size_t)r * 256 + sc * 8, refl + i * 512);
            }
        }
        __syncthreads();

        short8 bhi[2][4], blo[2][4];
        #pragma unroll
        for (int ptile = 0; ptile < 2; ++ptile) {
            int r = ptile * 16 + (lane & 15);
            #pragma unroll
            for (int ks = 0; ks < 4; ++ks) {
                int cg = ks * 4 + (lane >> 4);
                const char* p = (const char*)refl + r * 512 + ((cg ^ (r & 7)) << 4);
                bhi[ptile][ks] = *(const short8*)p;
                blo[ptile][ks] = *(const short8*)(p + 256);
            }
        }

        f32x4 acc[2][2];
        #pragma unroll
        for (int ptile = 0; ptile < 2; ++ptile)
            #pragma unroll
            for (int j = 0; j < 2; ++j) acc[ptile][j] = (f32x4){0.f, 0.f, 0.f, 0.f};

        #pragma unroll
        for (int ks = 0; ks < 4; ++ks) {
            #pragma unroll
            for (int ptile = 0; ptile < 2; ++ptile)
                #pragma unroll
                for (int j = 0; j < 2; ++j)
                    acc[ptile][j] = __builtin_amdgcn_mfma_f32_16x16x32_bf16(
                        ahi[j][ks], bhi[ptile][ks], acc[ptile][j], 0, 0, 0);
            #pragma unroll
            for (int ptile = 0; ptile < 2; ++ptile)
                #pragma unroll
                for (int j = 0; j < 2; ++j)
                    acc[ptile][j] = __builtin_amdgcn_mfma_f32_16x16x32_bf16(
                        ahi[j][ks], blo[ptile][ks], acc[ptile][j], 0, 0, 0);
            #pragma unroll
            for (int ptile = 0; ptile < 2; ++ptile)
                #pragma unroll
                for (int j = 0; j < 2; ++j)
                    acc[ptile][j] = __builtin_amdgcn_mfma_f32_16x16x32_bf16(
                        alo[j][ks], bhi[ptile][ks], acc[ptile][j], 0, 0, 0);
        }

        #pragma unroll
        for (int ptile = 0; ptile < 2; ++ptile) {
            float nav = na[pbase + pc * 32 + ptile * 16 + (lane & 15)];
            #pragma unroll
            for (int j = 0; j < 2; ++j)
                #pragma unroll
                for (int r = 0; r < 4; ++r)
                    dmin[j][r] = fminf(dmin[j][r], fmaf(-2.f, acc[ptile][j][r], nav));
        }
    }

    // cross-lane min over the 16 p-columns, add nb, clamp, combine across ps-blocks
    #pragma unroll
    for (int j = 0; j < 2; ++j)
        #pragma unroll
        for (int r = 0; r < 4; ++r) {
            float v = dmin[j][r];
            v = fminf(v, __shfl_xor(v, 1, 64));
            v = fminf(v, __shfl_xor(v, 2, 64));
            v = fminf(v, __shfl_xor(v, 4, 64));
            v = fminf(v, __shfl_xor(v, 8, 64));
            if ((lane & 15) == 0) {
                int q = qbase + wave * 32 + j * 16 + 4 * (lane >> 4) + r;
                float d2 = fmaxf(v + nb[q], 0.f);
                atomicMin(&outd[q], __float_as_uint(d2));
            }
        }
}

// ============ final dsh conv (with inline distance->value map) ============
__global__ void k_final(const float* __restrict__ x3s, const unsigned* __restrict__ gmd,
                        const unsigned* __restrict__ lmd, const float* __restrict__ x2,
                        const float* __restrict__ dshw, const float* __restrict__ dshb,
                        float* __restrict__ out) {
    int idx = blockIdx.x * THREADS + threadIdx.x;   // 4*2304
    if (idx >= 9216) return;
    int q = idx % HW, ni = idx / HW;
    int n = 2 + (ni & 1) + 4 * (ni >> 1);
    int b = ni >> 1;
    int x = q % 48, y = q / 48;
    float acc = dshb[0];
    for (int c = 0; c < 7; ++c) {
        const float* wp = dshw + c * 9;
        #pragma unroll
        for (int ky = 0; ky < 3; ++ky) {
            int yy = y + ky - 1;
            if (yy < 0 || yy >= 48) continue;
            #pragma unroll
            for (int kx = 0; kx < 3; ++kx) {
                int xx = x + kx - 1;
                if (xx < 0 || xx >= 48) continue;
                float v;
                if (c < 4) v = x3s[(size_t)(b * 4 + c) * HW + yy * 48 + xx];
                else if (c == 4) {
                    float d2 = __uint_as_float(gmd[(size_t)ni * HW + yy * 48 + xx]);
                    v = 1.f - 2.f / (1.f + expf(d2));
                } else if (c == 5) {
                    float d2 = __uint_as_float(lmd[(size_t)ni * HW + yy * 48 + xx]);
                    v = 1.f - 2.f / (1.f + expf(d2));
                } else v = x2[(size_t)n * HW + yy * 48 + xx];
                acc = fmaf(v, wp[ky * 3 + kx], acc);
            }
        }
    }
    out[idx] = acc;
}

extern "C" void kernel_launch(void* const* d_in, const int* in_sizes, int n_in,
                              void* d_out, int out_size, void* d_ws, size_t ws_size,
                              hipStream_t stream) {
    const float* x1     = (const float*)d_in[0];
    const float* x2     = (const float*)d_in[1];
    const float* x3     = (const float*)d_in[2];
    const float* enc1_w = (const float*)d_in[3];
    const float* enc1_b = (const float*)d_in[4];
    const float* enc2_w = (const float*)d_in[5];
    const float* enc2_b = (const float*)d_in[6];
    const float* bott_w = (const float*)d_in[7];
    const float* bott_b = (const float*)d_in[8];
    const float* dec2_w = (const float*)d_in[9];
    const float* dec2_b = (const float*)d_in[10];
    const float* dec1_w = (const float*)d_in[11];
    const float* dec1_b = (const float*)d_in[12];
    const float* out_w  = (const float*)d_in[13];
    const float* out_b  = (const float*)d_in[14];
    const float* emb_w  = (const float*)d_in[15];
    const float* emb_b  = (const float*)d_in[16];
    const float* dsh_w  = (const float*)d_in[17];
    const float* dsh_b  = (const float*)d_in[18];

    float* w = (float*)d_ws;
    float* e1u  = w;                   // 73728
    float* p1   = w + 73728;           // 18432
    float* e2   = w + 92160;           // 36864
    float* p2   = w + 129024;          // 9216
    float* bt   = w + 138240;          // 18432
    float* d2b  = w + 156672;          // 36864
    float* x3s  = w + 193536;          // 18432
    float* nrm  = w + 211968;          // 27648
    unsigned* gmd = (unsigned*)(w + 239616);   // 9216
    unsigned* lmd = (unsigned*)(w + 248832);   // 9216
    unsigned short* hl = (unsigned short*)(w + 258048);  // 3*4*2304*256 ushorts

    k_enc1pool<<<dim3(72), dim3(THREADS), 0, stream>>>(x3, enc1_w, enc1_b, e1u, p1);
    k_enc2pool<<<dim3(36), dim3(THREADS), 0, stream>>>(p1, enc2_w, enc2_b, e2, p2);
    k_bott<<<dim3(72), dim3(THREADS), 0, stream>>>(p2, bott_w, bott_b, bt);
    k_dec2<<<dim3(144), dim3(THREADS), 0, stream>>>(bt, e2, dec2_w, dec2_b, d2b);
    k_dec1out<<<dim3(144), dim3(THREADS), 0, stream>>>(d2b, e1u, dec1_w, dec1_b, out_w, out_b, x3s);
    k_embprep<<<dim3(180), dim3(THREADS), 0, stream>>>(x1, x2, x3s, emb_w, emb_b, hl, nrm, gmd);
    k_match<<<dim3(432), dim3(THREADS), 0, stream>>>(hl, nrm, gmd, lmd);
    k_final<<<dim3(36), dim3(THREADS), 0, stream>>>(x3s, gmd, lmd, x2, dsh_w, dsh_b, (float*)d_out);
}

// Round 3
// 148.841 us; speedup vs baseline: 3.2344x; 1.9202x over previous
//
#include <hip/hip_runtime.h>
#include <math.h>

#define THREADS 256
#define HW 2304

typedef __attribute__((ext_vector_type(8))) short short8;
typedef __attribute__((ext_vector_type(4))) float f32x4;
typedef __attribute__((ext_vector_type(8))) unsigned short us8;

typedef const __attribute__((address_space(1))) void* gas_p;
typedef __attribute__((address_space(3))) void* las_p;

__device__ __forceinline__ void gll16(const void* g, const void* l) {
    __builtin_amdgcn_global_load_lds((gas_p)g, (las_p)l, 16, 0, 0);
}

// ---- generic LDS staging: rows [rlo, rlo+rcount) of each channel, zero-padded,
//      row layout: 2 left-pad + W + 2 right-pad (rowfl = W+4, multiple of 4) ----
__device__ __forceinline__ void stage_rows(const float* __restrict__ src, float* __restrict__ dst,
                                           int nch, int chStride, int H, int W,
                                           int rlo, int rcount, int tid, int nthr, bool relu) {
    int rowfl = W + 4;
    int total = nch * rcount * rowfl;           // multiple of 4
    float4 z = make_float4(0.f, 0.f, 0.f, 0.f);
    for (int i = tid; i * 4 < total; i += nthr) ((float4*)dst)[i] = z;
    __syncthreads();
    int w2 = W >> 1;
    int m = nch * rcount * w2;
    for (int i = tid; i < m; i += nthr) {
        int c2 = i % w2;
        int rr = (i / w2) % rcount;
        int ch = i / (w2 * rcount);
        int srow = rlo + rr;
        if (srow < 0 || srow >= H) continue;
        float2 v = *(const float2*)(src + (size_t)ch * chStride + srow * W + 2 * c2);
        if (relu) { v.x = fmaxf(v.x, 0.f); v.y = fmaxf(v.y, 0.f); }
        *(float2*)(dst + (size_t)ch * rcount * rowfl + rr * rowfl + 2 + 2 * c2) = v;
    }
    __syncthreads();
}

#define LOAD_W9(wlbase, ci)                                        \
    const float4* wp4 = (const float4*)((wlbase) + (ci) * 12);     \
    float4 wa = wp4[0], wb = wp4[1], wc = wp4[2];                  \
    const float w9[9] = {wa.x, wa.y, wa.z, wa.w, wb.x, wb.y, wb.z, wb.w, wc.x};

// ---- init accumulation buffers with bias ----
__global__ void k_init(float* __restrict__ d2b, float* __restrict__ d1b,
                       const float* __restrict__ b2, const float* __restrict__ b1) {
    int idx = blockIdx.x * THREADS + threadIdx.x;
    if (idx < 36864) {
        d2b[idx] = b2[(idx / 576) & 31];
    } else if (idx < 110592) {
        int j = idx - 36864;
        d1b[j] = b1[(j / HW) & 15];
    }
}

// ---- enc1: conv3x3(Cin=3)+relu -> e1u, fused pool -> p1. grid 32 = n2*co16 ----
__global__ __launch_bounds__(192) void k_enc1pool(const float* __restrict__ x3, const float* __restrict__ w,
                                                  const float* __restrict__ b, float* __restrict__ e1u,
                                                  float* __restrict__ p1) {
    int co = blockIdx.x & 15, n = blockIdx.x >> 4;
    int tid = threadIdx.x;
    __shared__ __align__(16) float lds[3 * 50 * 52];
    __shared__ __align__(16) float wl[48];
    for (int i = tid; i < 27; i += 192) wl[(i / 9) * 12 + (i % 9)] = w[(co * 3) * 9 + i];
    stage_rows(x3 + (size_t)n * 3 * HW, lds, 3, HW, 48, 48, -1, 50, tid, 192, false);
    float bv = b[co];
    for (int o = 0; o < 3; ++o) {
        int po = o * 192 + tid;
        int py = po / 24, px = po % 24;
        float s[2][2] = {{bv, bv}, {bv, bv}};
        for (int ci = 0; ci < 3; ++ci) {
            const float* chp = lds + ci * 2600;
            float c[4][6];
            #pragma unroll
            for (int rr = 0; rr < 4; ++rr) {
                const float2* pr = (const float2*)(chp + (2 * py + rr) * 52);
                #pragma unroll
                for (int k = 0; k < 3; ++k) { float2 t = pr[px + k]; c[rr][2 * k] = t.x; c[rr][2 * k + 1] = t.y; }
            }
            LOAD_W9(wl, ci)
            #pragma unroll
            for (int dy = 0; dy < 3; ++dy)
                #pragma unroll
                for (int dx = 0; dx < 3; ++dx) {
                    float wv = w9[dy * 3 + dx];
                    #pragma unroll
                    for (int yy = 0; yy < 2; ++yy)
                        #pragma unroll
                        for (int xx = 0; xx < 2; ++xx)
                            s[yy][xx] = fmaf(c[yy + dy][xx + dx + 1], wv, s[yy][xx]);
                }
        }
        float* ob = e1u + (size_t)(n * 16 + co) * HW;
        float mx = -INFINITY;
        #pragma unroll
        for (int yy = 0; yy < 2; ++yy)
            #pragma unroll
            for (int xx = 0; xx < 2; ++xx) {
                float v = fmaxf(s[yy][xx], 0.f);
                ob[(2 * py + yy) * 48 + 2 * px + xx] = v;
                mx = fmaxf(mx, v);
            }
        p1[(size_t)(n * 16 + co) * 576 + py * 24 + px] = mx;
    }
}

// ---- enc2: conv3x3(Cin=16 @24)+relu -> e2, fused pool -> p2. grid 64 = n2*co32 ----
__global__ __launch_bounds__(192) void k_enc2pool(const float* __restrict__ p1, const float* __restrict__ w,
                                                  const float* __restrict__ b, float* __restrict__ e2,
                                                  float* __restrict__ p2) {
    int co = blockIdx.x & 31, n = blockIdx.x >> 5;
    int tid = threadIdx.x;
    __shared__ __align__(16) float lds[16 * 26 * 28];
    __shared__ __align__(16) float wl[192];
    for (int i = tid; i < 144; i += 192) wl[(i / 9) * 12 + (i % 9)] = w[(co * 16) * 9 + i];
    stage_rows(p1 + (size_t)n * 16 * 576, lds, 16, 576, 24, 24, -1, 26, tid, 192, false);
    if (tid < 144) {
        int py = tid / 12, px = tid % 12;
        float bv = b[co];
        float s[2][2] = {{bv, bv}, {bv, bv}};
        for (int ci = 0; ci < 16; ++ci) {
            const float* chp = lds + ci * 728;
            float c[4][6];
            #pragma unroll
            for (int rr = 0; rr < 4; ++rr) {
                const float2* pr = (const float2*)(chp + (2 * py + rr) * 28);
                #pragma unroll
                for (int k = 0; k < 3; ++k) { float2 t = pr[px + k]; c[rr][2 * k] = t.x; c[rr][2 * k + 1] = t.y; }
            }
            LOAD_W9(wl, ci)
            #pragma unroll
            for (int dy = 0; dy < 3; ++dy)
                #pragma unroll
                for (int dx = 0; dx < 3; ++dx) {
                    float wv = w9[dy * 3 + dx];
                    #pragma unroll
                    for (int yy = 0; yy < 2; ++yy)
                        #pragma unroll
                        for (int xx = 0; xx < 2; ++xx)
                            s[yy][xx] = fmaf(c[yy + dy][xx + dx + 1], wv, s[yy][xx]);
                }
        }
        float* ob = e2 + (size_t)(n * 32 + co) * 576;
        float mx = -INFINITY;
        #pragma unroll
        for (int yy = 0; yy < 2; ++yy)
            #pragma unroll
            for (int xx = 0; xx < 2; ++xx) {
                float v = fmaxf(s[yy][xx], 0.f);
                ob[(2 * py + yy) * 24 + 2 * px + xx] = v;
                mx = fmaxf(mx, v);
            }
        p2[(size_t)(n * 32 + co) * 144 + py * 12 + px] = mx;
    }
}

// ---- bottleneck: conv3x3(Cin=32 @12)+relu -> bt. grid 128 = n2*co64 ----
__global__ __launch_bounds__(192) void k_bott(const float* __restrict__ p2, const float* __restrict__ w,
                                              const float* __restrict__ b, float* __restrict__ bt) {
    int co = blockIdx.x & 63, n = blockIdx.x >> 6;
    int tid = threadIdx.x;
    __shared__ __align__(16) float lds[32 * 14 * 16];
    __shared__ __align__(16) float wl[384];
    for (int i = tid; i < 288; i += 192) wl[(i / 9) * 12 + (i % 9)] = w[(co * 32) * 9 + i];
    stage_rows(p2 + (size_t)n * 32 * 144, lds, 32, 144, 12, 12, -1, 14, tid, 192, false);
    if (tid < 144) {
        int y = tid / 12, x = tid % 12;
        float acc = b[co];
        for (int ci = 0; ci < 32; ++ci) {
            const float* chp = lds + ci * 224;
            LOAD_W9(wl, ci)
            #pragma unroll
            for (int dy = 0; dy < 3; ++dy)
                #pragma unroll
                for (int dx = 0; dx < 3; ++dx)
                    acc = fmaf(chp[(y + dy) * 16 + x + dx + 1], w9[dy * 3 + dx], acc);
        }
        bt[(size_t)(n * 64 + co) * 144 + y * 12 + x] = fmaxf(acc, 0.f);
    }
}

// ---- dec2 partial: conv3x3 over concat(up(bt)[64], e2[32]); ci-chunked, atomicAdd.
//      grid 256 = chunk4 | co32 | n2; block 192 (144 compute quads) ----
__global__ __launch_bounds__(192) void k_dec2p(const float* __restrict__ bt, const float* __restrict__ e2,
                                               const float* __restrict__ w, float* __restrict__ d2b) {
    int bx = blockIdx.x;
    int chunk = bx & 3, co = (bx >> 2) & 31, n = bx >> 7;
    int cib = chunk * 24;
    int nA = max(0, min(24, 64 - cib));
    int nB = 24 - nA;
    int tid = threadIdx.x;
    __shared__ __align__(16) float lds[24 * 26 * 28];
    __shared__ __align__(16) float wl[288];
    for (int i = tid; i < 216; i += 192) wl[(i / 9) * 12 + (i % 9)] = w[((size_t)co * 96 + cib) * 9 + i];
    stage_rows(bt + ((size_t)n * 64 + cib) * 144, lds, nA, 144, 12, 12, -1, 14, tid, 192, false);
    float* ldsB = lds + nA * 224;
    int e2c = max(0, cib + nA - 64);
    stage_rows(e2 + ((size_t)n * 32 + e2c) * 576, ldsB, nB, 576, 24, 24, -1, 26, tid, 192, false);
    if (tid < 144) {
        int y = tid / 6, qx = tid % 6;
        float acc[4] = {0.f, 0.f, 0.f, 0.f};
        int r0 = ((y - 1) >> 1) + 1;
        int yodd = y & 1;
        for (int ci = 0; ci < nA; ++ci) {
            const float* chp = lds + ci * 224;
            const float2* p0 = (const float2*)(chp + r0 * 16);
            const float2* p1 = (const float2*)(chp + (r0 + 1) * 16);
            float a0[6], a1[6], am[6];
            #pragma unroll
            for (int k = 0; k < 3; ++k) {
                float2 t0 = p0[qx + k], t1 = p1[qx + k];
                a0[2 * k] = t0.x; a0[2 * k + 1] = t0.y;
                a1[2 * k] = t1.x; a1[2 * k + 1] = t1.y;
            }
            #pragma unroll
            for (int k = 0; k < 6; ++k) am[k] = yodd ? a0[k] : a1[k];
            LOAD_W9(wl, ci)
            #pragma unroll
            for (int dy = 0; dy < 3; ++dy) {
                const float* rr = (dy == 0) ? a0 : (dy == 1 ? am : a1);
                #pragma unroll
                for (int dx = 0; dx < 3; ++dx) {
                    float wv = w9[dy * 3 + dx];
                    #pragma unroll
                    for (int j = 0; j < 4; ++j)
                        acc[j] = fmaf(rr[((j + dx - 1) >> 1) + 2], wv, acc[j]);
                }
            }
        }
        for (int ci = 0; ci < nB; ++ci) {
            const float* chp = ldsB + ci * 728;
            float bvv[3][8];
            #pragma unroll
            for (int r = 0; r < 3; ++r) {
                const float2* pr = (const float2*)(chp + (y + r) * 28);
                #pragma unroll
                for (int k = 0; k < 4; ++k) { float2 t = pr[2 * qx + k]; bvv[r][2 * k] = t.x; bvv[r][2 * k + 1] = t.y; }
            }
            LOAD_W9(wl, nA + ci)
            #pragma unroll
            for (int dy = 0; dy < 3; ++dy)
                #pragma unroll
                for (int dx = 0; dx < 3; ++dx) {
                    float wv = w9[dy * 3 + dx];
                    #pragma unroll
                    for (int j = 0; j < 4; ++j)
                        acc[j] = fmaf(bvv[dy][j + dx + 1], wv, acc[j]);
                }
        }
        float* op = d2b + ((size_t)(n * 32 + co)) * 576 + y * 24 + qx * 4;
        #pragma unroll
        for (int j = 0; j < 4; ++j) atomicAdd(op + j, acc[j]);
    }
}

// ---- dec1 partial: conv3x3 over concat(up(relu(d2b))[32], e1u[16]); atomicAdd.
//      grid 384 = strip3 | chunk4 | co16 | n2; block 192 (all compute) ----
__global__ __launch_bounds__(192) void k_dec1p(const float* __restrict__ d2b, const float* __restrict__ e1u,
                                               const float* __restrict__ w, float* __restrict__ d1b) {
    int bx = blockIdx.x;
    int strip = bx % 3;
    int chunk = (bx / 3) & 3;
    int co = (bx / 12) & 15;
    int n = bx / 192;
    int cib = chunk * 12;
    int nA = max(0, min(12, 32 - cib));
    int nB = 12 - nA;
    int y0 = strip * 16;
    int yhlo = (y0 - 1) >> 1;
    int tid = threadIdx.x;
    __shared__ __align__(16) float lds[12 * 18 * 52];
    __shared__ __align__(16) float wl[144];
    for (int i = tid; i < 108; i += 192) wl[(i / 9) * 12 + (i % 9)] = w[((size_t)co * 48 + cib) * 9 + i];
    stage_rows(d2b + ((size_t)n * 32 + cib) * 576, lds, nA, 576, 24, 24, yhlo, 10, tid, 192, true);
    float* ldsB = lds + nA * 280;
    int e1c = max(0, cib + nA - 32);
    stage_rows(e1u + ((size_t)n * 16 + e1c) * HW, ldsB, nB, HW, 48, 48, y0 - 1, 18, tid, 192, false);
    {
        int yl = tid / 12, qx = tid % 12;
        int y = y0 + yl;
        float acc[4] = {0.f, 0.f, 0.f, 0.f};
        int r0 = ((y - 1) >> 1) - yhlo;
        int yodd = y & 1;
        for (int ci = 0; ci < nA; ++ci) {
            const float* chp = lds + ci * 280;
            const float2* p0 = (const float2*)(chp + r0 * 28);
            const float2* p1 = (const float2*)(chp + (r0 + 1) * 28);
            float a0[6], a1[6], am[6];
            #pragma unroll
            for (int k = 0; k < 3; ++k) {
                float2 t0 = p0[qx + k], t1 = p1[qx + k];
                a0[2 * k] = t0.x; a0[2 * k + 1] = t0.y;
                a1[2 * k] = t1.x; a1[2 * k + 1] = t1.y;
            }
            #pragma unroll
            for (int k = 0; k < 6; ++k) am[k] = yodd ? a0[k] : a1[k];
            LOAD_W9(wl, ci)
            #pragma unroll
            for (int dy = 0; dy < 3; ++dy) {
                const float* rr = (dy == 0) ? a0 : (dy == 1 ? am : a1);
                #pragma unroll
                for (int dx = 0; dx < 3; ++dx) {
                    float wv = w9[dy * 3 + dx];
                    #pragma unroll
                    for (int j = 0; j < 4; ++j)
                        acc[j] = fmaf(rr[((j + dx - 1) >> 1) + 2], wv, acc[j]);
                }
            }
        }
        for (int ci = 0; ci < nB; ++ci) {
            const float* chp = ldsB + ci * 936;
            float bvv[3][8];
            #pragma unroll
            for (int r = 0; r < 3; ++r) {
                const float2* pr = (const float2*)(chp + (yl + r) * 52);
                #pragma unroll
                for (int k = 0; k < 4; ++k) { float2 t = pr[2 * qx + k]; bvv[r][2 * k] = t.x; bvv[r][2 * k + 1] = t.y; }
            }
            LOAD_W9(wl, nA + ci)
            #pragma unroll
            for (int dy = 0; dy < 3; ++dy)
                #pragma unroll
                for (int dx = 0; dx < 3; ++dx) {
                    float wv = w9[dy * 3 + dx];
                    #pragma unroll
                    for (int j = 0; j < 4; ++j)
                        acc[j] = fmaf(bvv[dy][j + dx + 1], wv, acc[j]);
                }
        }
        float* op = d1b + ((size_t)(n * 16 + co)) * HW + y * 48 + qx * 4;
        #pragma unroll
        for (int j = 0; j < 4; ++j) atomicAdd(op + j, acc[j]);
    }
}

// ---- out 1x1 conv over relu(d1b) -> x3s ----
__global__ void k_out1x1(const float* __restrict__ d1b, const float* __restrict__ ow,
                         const float* __restrict__ ob, float* __restrict__ x3s) {
    int idx = blockIdx.x * THREADS + threadIdx.x;
    if (idx >= 18432) return;
    int q = idx % HW;
    int co = (idx / HW) & 3;
    int n = idx / 9216;
    float acc = ob[co];
    #pragma unroll
    for (int ci = 0; ci < 16; ++ci)
        acc = fmaf(fmaxf(d1b[((size_t)(n * 16 + ci)) * HW + q], 0.f), ow[co * 16 + ci], acc);
    x3s[((size_t)(n * 4 + co)) * HW + q] = acc;
}

// ============ embedding conv + norm + bf16 hi/lo split (+ dmin init) ============
__global__ __launch_bounds__(THREADS) void k_embprep(
        const float* __restrict__ x1, const float* __restrict__ x2,
        const float* __restrict__ x3s, const float* __restrict__ ew,
        const float* __restrict__ eb, unsigned short* __restrict__ hl,
        float* __restrict__ nrm, unsigned* __restrict__ initbuf) {
    int bx = blockIdx.x;
    int tid = threadIdx.x;
    if (bx >= 108) {
        int i = (bx - 108) * THREADS + tid;
        if (i < 2 * 4 * HW) initbuf[i] = 0x7F800000u;
        return;
    }
    int pt = bx % 9, ni = (bx / 9) % 4, arr = bx / 36;
    int plane = 2 + (ni & 1) + 4 * (ni >> 1);
    const float* src = (arr == 0 ? x1 : (arr == 1 ? x2 : x3s)) + (size_t)plane * HW;

    __shared__ float wl[1300];
    for (int i = tid; i < 900; i += THREADS) wl[(i / 9) * 12 + (i % 9)] = ew[i];
    for (int i = tid; i < 100; i += THREADS) wl[1200 + i] = eb[i];
    __syncthreads();

    int pix = pt * THREADS + tid;
    int x = pix % 48, y = pix / 48;
    float p9[9];
    #pragma unroll
    for (int ky = 0; ky < 3; ++ky)
        #pragma unroll
        for (int kx = 0; kx < 3; ++kx) {
            int yy = y + ky - 1, xx = x + kx - 1;
            p9[ky * 3 + kx] = (yy >= 0 && yy < 48 && xx >= 0 && xx < 48) ? src[yy * 48 + xx] : 0.f;
        }

    float nsum = 0.f;
    char* rowp = (char*)(hl + (((size_t)(arr * 4 + ni)) * HW + pix) * 256);
    for (int g = 0; g < 16; ++g) {
        us8 vh, vl;
        #pragma unroll
        for (int j = 0; j < 8; ++j) {
            int e = g * 8 + j;
            float v = 0.f;
            if (e < 100) {
                v = wl[1200 + e];
                #pragma unroll
                for (int k = 0; k < 9; ++k) v = fmaf(p9[k], wl[e * 12 + k], v);
                nsum = fmaf(v, v, nsum);
            }
            unsigned bits = __float_as_uint(v);
            vh[j] = (unsigned short)(bits >> 16);
            float lo = v - __uint_as_float(bits & 0xFFFF0000u);
            vl[j] = (unsigned short)(__float_as_uint(lo) >> 16);
        }
        *(us8*)(rowp + g * 16) = vh;
        *(us8*)(rowp + 256 + g * 16) = vl;
    }
    nrm[(size_t)(arr * 4 + ni) * HW + pix] = nsum;
}

// ================= global matching via split-bf16 MFMA =================
__global__ __launch_bounds__(THREADS) void k_match(
        const unsigned short* __restrict__ hl, const float* __restrict__ nrm,
        unsigned* __restrict__ gmd, unsigned* __restrict__ lmd) {
    int bx = blockIdx.x;
    int ps = bx % 3;
    int rest = bx / 3;
    int qt = rest % 18;
    int n = (rest / 18) % 4;
    int m = rest / 72;

    const unsigned short* curhl = hl + ((size_t)(8 + n)) * HW * 256;
    const unsigned short* refhl = hl + ((size_t)(m * 4 + n)) * HW * 256;
    const float* na = nrm + (size_t)(m * 4 + n) * HW;
    const float* nb = nrm + (size_t)(8 + n) * HW;
    unsigned* outd = (m == 0 ? gmd : lmd) + (size_t)n * HW;

    int qbase = qt * 128;
    int pbase = ps * 768;

    __shared__ unsigned short lds[(128 + 32) * 256];
    unsigned short* curl = lds;
    unsigned short* refl = lds + 128 * 256;

    int tid = threadIdx.x;
    int wave = tid >> 6;
    int lane = tid & 63;
    int lr = lane >> 5;
    int lc = lane & 31;

    {
        const unsigned short* gb = curhl + (size_t)qbase * 256;
        for (int t = 0; t < 16; ++t) {
            int i = wave * 16 + t;
            int r = 2 * i + lr;
            int sc = lc ^ (r & 7);
            gll16(gb + (size_t)r * 256 + sc * 8, curl + i * 512);
        }
    }
    __syncthreads();

    short8 ahi[2][4], alo[2][4];
    #pragma unroll
    for (int j = 0; j < 2; ++j) {
        int r = wave * 32 + j * 16 + (lane & 15);
        #pragma unroll
        for (int ks = 0; ks < 4; ++ks) {
            int cg = ks * 4 + (lane >> 4);
            const char* p = (const char*)curl + r * 512 + ((cg ^ (r & 7)) << 4);
            ahi[j][ks] = *(const short8*)p;
            alo[j][ks] = *(const short8*)(p + 256);
        }
    }

    float dmin[2][4];
    #pragma unroll
    for (int j = 0; j < 2; ++j)
        #pragma unroll
        for (int r = 0; r < 4; ++r) dmin[j][r] = INFINITY;

    for (int pc = 0; pc < 24; ++pc) {
        __syncthreads();
        {
            const unsigned short* gb = refhl + (size_t)(pbase + pc * 32) * 256;
            for (int t = 0; t < 4; ++t) {
                int i = wave * 4 + t;
                int r = 2 * i + lr;
                int sc = lc ^ (r & 7);
                gll16(gb + (size_t)r * 256 + sc * 8, refl + i * 512);
            }
        }
        __syncthreads();

        short8 bhi[2][4], blo[2][4];
        #pragma unroll
        for (int ptile = 0; ptile < 2; ++ptile) {
            int r = ptile * 16 + (lane & 15);
            #pragma unroll
            for (int ks = 0; ks < 4; ++ks) {
                int cg = ks * 4 + (lane >> 4);
                const char* p = (const char*)refl + r * 512 + ((cg ^ (r & 7)) << 4);
                bhi[ptile][ks] = *(const short8*)p;
                blo[ptile][ks] = *(const short8*)(p + 256);
            }
        }

        f32x4 acc[2][2];
        #pragma unroll
        for (int ptile = 0; ptile < 2; ++ptile)
            #pragma unroll
            for (int j = 0; j < 2; ++j) acc[ptile][j] = (f32x4){0.f, 0.f, 0.f, 0.f};

        #pragma unroll
        for (int ks = 0; ks < 4; ++ks) {
            #pragma unroll
            for (int ptile = 0; ptile < 2; ++ptile)
                #pragma unroll
                for (int j = 0; j < 2; ++j)
                    acc[ptile][j] = __builtin_amdgcn_mfma_f32_16x16x32_bf16(
                        ahi[j][ks], bhi[ptile][ks], acc[ptile][j], 0, 0, 0);
            #pragma unroll
            for (int ptile = 0; ptile < 2; ++ptile)
                #pragma unroll
                for (int j = 0; j < 2; ++j)
                    acc[ptile][j] = __builtin_amdgcn_mfma_f32_16x16x32_bf16(
                        ahi[j][ks], blo[ptile][ks], acc[ptile][j], 0, 0, 0);
            #pragma unroll
            for (int ptile = 0; ptile < 2; ++ptile)
                #pragma unroll
                for (int j = 0; j < 2; ++j)
                    acc[ptile][j] = __builtin_amdgcn_mfma_f32_16x16x32_bf16(
                        alo[j][ks], bhi[ptile][ks], acc[ptile][j], 0, 0, 0);
        }

        #pragma unroll
        for (int ptile = 0; ptile < 2; ++ptile) {
            float nav = na[pbase + pc * 32 + ptile * 16 + (lane & 15)];
            #pragma unroll
            for (int j = 0; j < 2; ++j)
                #pragma unroll
                for (int r = 0; r < 4; ++r)
                    dmin[j][r] = fminf(dmin[j][r], fmaf(-2.f, acc[ptile][j][r], nav));
        }
    }

    #pragma unroll
    for (int j = 0; j < 2; ++j)
        #pragma unroll
        for (int r = 0; r < 4; ++r) {
            float v = dmin[j][r];
            v = fminf(v, __shfl_xor(v, 1, 64));
            v = fminf(v, __shfl_xor(v, 2, 64));
            v = fminf(v, __shfl_xor(v, 4, 64));
            v = fminf(v, __shfl_xor(v, 8, 64));
            if ((lane & 15) == 0) {
                int q = qbase + wave * 32 + j * 16 + 4 * (lane >> 4) + r;
                float d2 = fmaxf(v + nb[q], 0.f);
                atomicMin(&outd[q], __float_as_uint(d2));
            }
        }
}

// ============ final dsh conv (with inline distance->value map) ============
__global__ void k_final(const float* __restrict__ x3s, const unsigned* __restrict__ gmd,
                        const unsigned* __restrict__ lmd, const float* __restrict__ x2,
                        const float* __restrict__ dshw, const float* __restrict__ dshb,
                        float* __restrict__ out) {
    int idx = blockIdx.x * THREADS + threadIdx.x;
    if (idx >= 9216) return;
    int q = idx % HW, ni = idx / HW;
    int n = 2 + (ni & 1) + 4 * (ni >> 1);
    int b = ni >> 1;
    int x = q % 48, y = q / 48;
    float acc = dshb[0];
    for (int c = 0; c < 7; ++c) {
        const float* wp = dshw + c * 9;
        #pragma unroll
        for (int ky = 0; ky < 3; ++ky) {
            int yy = y + ky - 1;
            if (yy < 0 || yy >= 48) continue;
            #pragma unroll
            for (int kx = 0; kx < 3; ++kx) {
                int xx = x + kx - 1;
                if (xx < 0 || xx >= 48) continue;
                float v;
                if (c < 4) v = x3s[(size_t)(b * 4 + c) * HW + yy * 48 + xx];
                else if (c == 4) {
                    float d2 = __uint_as_float(gmd[(size_t)ni * HW + yy * 48 + xx]);
                    v = 1.f - 2.f / (1.f + expf(d2));
                } else if (c == 5) {
                    float d2 = __uint_as_float(lmd[(size_t)ni * HW + yy * 48 + xx]);
                    v = 1.f - 2.f / (1.f + expf(d2));
                } else v = x2[(size_t)n * HW + yy * 48 + xx];
                acc = fmaf(v, wp[ky * 3 + kx], acc);
            }
        }
    }
    out[idx] = acc;
}

extern "C" void kernel_launch(void* const* d_in, const int* in_sizes, int n_in,
                              void* d_out, int out_size, void* d_ws, size_t ws_size,
                              hipStream_t stream) {
    const float* x1     = (const float*)d_in[0];
    const float* x2     = (const float*)d_in[1];
    const float* x3     = (const float*)d_in[2];
    const float* enc1_w = (const float*)d_in[3];
    const float* enc1_b = (const float*)d_in[4];
    const float* enc2_w = (const float*)d_in[5];
    const float* enc2_b = (const float*)d_in[6];
    const float* bott_w = (const float*)d_in[7];
    const float* bott_b = (const float*)d_in[8];
    const float* dec2_w = (const float*)d_in[9];
    const float* dec2_b = (const float*)d_in[10];
    const float* dec1_w = (const float*)d_in[11];
    const float* dec1_b = (const float*)d_in[12];
    const float* out_w  = (const float*)d_in[13];
    const float* out_b  = (const float*)d_in[14];
    const float* emb_w  = (const float*)d_in[15];
    const float* emb_b  = (const float*)d_in[16];
    const float* dsh_w  = (const float*)d_in[17];
    const float* dsh_b  = (const float*)d_in[18];

    float* w = (float*)d_ws;
    float* e1u  = w;                   // 73728
    float* p1   = w + 73728;           // 18432
    float* e2   = w + 92160;           // 36864
    float* p2   = w + 129024;          // 9216
    float* bt   = w + 138240;          // 18432
    float* d2b  = w + 156672;          // 36864
    float* d1b  = w + 193536;          // 73728 (ends 267264)
    float* x3s  = w + 267264;          // 18432
    float* nrm  = w + 285696;          // 27648
    unsigned* gmd = (unsigned*)(w + 313344);   // 9216
    unsigned* lmd = (unsigned*)(w + 322560);   // 9216
    unsigned short* hl = (unsigned short*)(w + 331776);  // 3*4*2304*256 ushorts

    k_init<<<dim3(432), dim3(THREADS), 0, stream>>>(d2b, d1b, dec2_b, dec1_b);
    k_enc1pool<<<dim3(32), dim3(192), 0, stream>>>(x3, enc1_w, enc1_b, e1u, p1);
    k_enc2pool<<<dim3(64), dim3(192), 0, stream>>>(p1, enc2_w, enc2_b, e2, p2);
    k_bott<<<dim3(128), dim3(192), 0, stream>>>(p2, bott_w, bott_b, bt);
    k_dec2p<<<dim3(256), dim3(192), 0, stream>>>(bt, e2, dec2_w, d2b);
    k_dec1p<<<dim3(384), dim3(192), 0, stream>>>(d2b, e1u, dec1_w, d1b);
    k_out1x1<<<dim3(72), dim3(THREADS), 0, stream>>>(d1b, out_w, out_b, x3s);
    k_embprep<<<dim3(180), dim3(THREADS), 0, stream>>>(x1, x2, x3s, emb_w, emb_b, hl, nrm, gmd);
    k_match<<<dim3(432), dim3(THREADS), 0, stream>>>(hl, nrm, gmd, lmd);
    k_final<<<dim3(36), dim3(THREADS), 0, stream>>>(x3s, gmd, lmd, x2, dsh_w, dsh_b, (float*)d_out);
}

// Round 4
// 136.820 us; speedup vs baseline: 3.5186x; 1.0879x over previous
//
#include <hip/hip_runtime.h>
#include <math.h>

#define THREADS 256
#define HW 2304

typedef __attribute__((ext_vector_type(8))) short short8;
typedef __attribute__((ext_vector_type(4))) float f32x4;
typedef __attribute__((ext_vector_type(8))) unsigned short us8;

typedef const __attribute__((address_space(1))) void* gas_p;
typedef __attribute__((address_space(3))) void* las_p;

__device__ __forceinline__ void gll16(const void* g, const void* l) {
    __builtin_amdgcn_global_load_lds((gas_p)g, (las_p)l, 16, 0, 0);
}

// ---- generic LDS staging: rows [rlo, rlo+rcount) of each channel, zero-padded,
//      row layout: 2 left-pad + W + 2 right-pad (rowfl = W+4, multiple of 4) ----
__device__ __forceinline__ void stage_rows(const float* __restrict__ src, float* __restrict__ dst,
                                           int nch, int chStride, int H, int W,
                                           int rlo, int rcount, int tid, int nthr, bool relu) {
    int rowfl = W + 4;
    int total = nch * rcount * rowfl;           // multiple of 4
    float4 z = make_float4(0.f, 0.f, 0.f, 0.f);
    for (int i = tid; i * 4 < total; i += nthr) ((float4*)dst)[i] = z;
    __syncthreads();
    int w2 = W >> 1;
    int m = nch * rcount * w2;
    for (int i = tid; i < m; i += nthr) {
        int c2 = i % w2;
        int rr = (i / w2) % rcount;
        int ch = i / (w2 * rcount);
        int srow = rlo + rr;
        if (srow < 0 || srow >= H) continue;
        float2 v = *(const float2*)(src + (size_t)ch * chStride + srow * W + 2 * c2);
        if (relu) { v.x = fmaxf(v.x, 0.f); v.y = fmaxf(v.y, 0.f); }
        *(float2*)(dst + (size_t)ch * rcount * rowfl + rr * rowfl + 2 + 2 * c2) = v;
    }
    __syncthreads();
}

#define LOAD_W9(wlbase, ci)                                        \
    const float4* wp4 = (const float4*)((wlbase) + (ci) * 12);     \
    float4 wa = wp4[0], wb = wp4[1], wc = wp4[2];                  \
    const float w9[9] = {wa.x, wa.y, wa.z, wa.w, wb.x, wb.y, wb.z, wb.w, wc.x};

// ---- embedding conv body: conv3x3(1->100) + norm + bf16 hi/lo split ----
__device__ __forceinline__ void emb_body(const float* __restrict__ src, int arr, int ni, int pt,
                                         const float* __restrict__ ew, const float* __restrict__ eb,
                                         unsigned short* __restrict__ hl, float* __restrict__ nrm,
                                         float* wl, int tid, int nthr) {
    for (int i = tid; i < 900; i += nthr) wl[(i / 9) * 12 + (i % 9)] = ew[i];
    for (int i = tid; i < 100; i += nthr) wl[1200 + i] = eb[i];
    __syncthreads();

    int pix = pt * 256 + tid;
    int x = pix % 48, y = pix / 48;
    float p9[9];
    #pragma unroll
    for (int ky = 0; ky < 3; ++ky)
        #pragma unroll
        for (int kx = 0; kx < 3; ++kx) {
            int yy = y + ky - 1, xx = x + kx - 1;
            p9[ky * 3 + kx] = (yy >= 0 && yy < 48 && xx >= 0 && xx < 48) ? src[yy * 48 + xx] : 0.f;
        }

    float nsum = 0.f;
    char* rowp = (char*)(hl + (((size_t)(arr * 4 + ni)) * HW + pix) * 256);
    for (int g = 0; g < 16; ++g) {
        us8 vh, vl;
        #pragma unroll
        for (int j = 0; j < 8; ++j) {
            int e = g * 8 + j;
            float v = 0.f;
            if (e < 100) {
                v = wl[1200 + e];
                #pragma unroll
                for (int k = 0; k < 9; ++k) v = fmaf(p9[k], wl[e * 12 + k], v);
                nsum = fmaf(v, v, nsum);
            }
            unsigned bits = __float_as_uint(v);
            vh[j] = (unsigned short)(bits >> 16);
            float lo = v - __uint_as_float(bits & 0xFFFF0000u);
            vl[j] = (unsigned short)(__float_as_uint(lo) >> 16);
        }
        *(us8*)(rowp + g * 16) = vh;
        *(us8*)(rowp + 256 + g * 16) = vl;
    }
    nrm[(size_t)(arr * 4 + ni) * HW + pix] = nsum;
}

// ---- fused front kernel: bias-init, embprep(x1,x2), dmin-init, enc1pool ----
// blocks: [0,432) init d2b/d1b | [432,504) embprep arr0/1 | [504,576) init inf | [576,608) enc1pool
__global__ __launch_bounds__(256) void k_pre(
        float* __restrict__ d2b, float* __restrict__ d1b,
        const float* __restrict__ b2, const float* __restrict__ b1,
        const float* __restrict__ x1, const float* __restrict__ x2,
        const float* __restrict__ ew, const float* __restrict__ eb,
        unsigned short* __restrict__ hl, float* __restrict__ nrm,
        unsigned* __restrict__ initbuf,
        const float* __restrict__ x3, const float* __restrict__ e1w,
        const float* __restrict__ e1b, float* __restrict__ e1u, float* __restrict__ p1) {
    __shared__ __align__(16) float lds[3 * 50 * 52];
    __shared__ __align__(16) float wl1[48];
    __shared__ float wl[1300];
    int bx = blockIdx.x;
    int tid = threadIdx.x;
    if (bx < 432) {
        int idx = bx * 256 + tid;
        if (idx < 36864) d2b[idx] = b2[(idx / 576) & 31];
        else d1b[idx - 36864] = b1[((idx - 36864) / HW) & 15];
        return;
    }
    if (bx < 504) {
        int sub = bx - 432;
        int arr = sub / 36;
        int ni = (sub % 36) / 9, pt = sub % 9;
        int plane = 2 + (ni & 1) + 4 * (ni >> 1);
        const float* src = (arr == 0 ? x1 : x2) + (size_t)plane * HW;
        emb_body(src, arr, ni, pt, ew, eb, hl, nrm, wl, tid, 256);
        return;
    }
    if (bx < 576) {
        int i = (bx - 504) * 256 + tid;
        initbuf[i] = 0x7F800000u;
        return;
    }
    // ---- enc1pool ----
    int co = (bx - 576) & 15, n = (bx - 576) >> 4;
    for (int i = tid; i < 27; i += 256) wl1[(i / 9) * 12 + (i % 9)] = e1w[(co * 3) * 9 + i];
    stage_rows(x3 + (size_t)n * 3 * HW, lds, 3, HW, 48, 48, -1, 50, tid, 256, false);
    float bv = e1b[co];
    for (int o = 0; o < 3; ++o) {
        int po = o * 256 + tid;
        if (po >= 576) break;
        int py = po / 24, px = po % 24;
        float s[2][2] = {{bv, bv}, {bv, bv}};
        for (int ci = 0; ci < 3; ++ci) {
            const float* chp = lds + ci * 2600;
            float c[4][6];
            #pragma unroll
            for (int rr = 0; rr < 4; ++rr) {
                const float2* pr = (const float2*)(chp + (2 * py + rr) * 52);
                #pragma unroll
                for (int k = 0; k < 3; ++k) { float2 t = pr[px + k]; c[rr][2 * k] = t.x; c[rr][2 * k + 1] = t.y; }
            }
            LOAD_W9(wl1, ci)
            #pragma unroll
            for (int dy = 0; dy < 3; ++dy)
                #pragma unroll
                for (int dx = 0; dx < 3; ++dx) {
                    float wv = w9[dy * 3 + dx];
                    #pragma unroll
                    for (int yy = 0; yy < 2; ++yy)
                        #pragma unroll
                        for (int xx = 0; xx < 2; ++xx)
                            s[yy][xx] = fmaf(c[yy + dy][xx + dx + 1], wv, s[yy][xx]);
                }
        }
        float* ob = e1u + (size_t)(n * 16 + co) * HW;
        float mx = -INFINITY;
        #pragma unroll
        for (int yy = 0; yy < 2; ++yy)
            #pragma unroll
            for (int xx = 0; xx < 2; ++xx) {
                float v = fmaxf(s[yy][xx], 0.f);
                ob[(2 * py + yy) * 48 + 2 * px + xx] = v;
                mx = fmaxf(mx, v);
            }
        p1[(size_t)(n * 16 + co) * 576 + py * 24 + px] = mx;
    }
}

// ---- enc2: conv3x3(Cin=16 @24)+relu -> e2, fused pool -> p2. grid 64 ----
__global__ __launch_bounds__(192) void k_enc2pool(const float* __restrict__ p1, const float* __restrict__ w,
                                                  const float* __restrict__ b, float* __restrict__ e2,
                                                  float* __restrict__ p2) {
    int co = blockIdx.x & 31, n = blockIdx.x >> 5;
    int tid = threadIdx.x;
    __shared__ __align__(16) float lds[16 * 26 * 28];
    __shared__ __align__(16) float wl[192];
    for (int i = tid; i < 144; i += 192) wl[(i / 9) * 12 + (i % 9)] = w[(co * 16) * 9 + i];
    stage_rows(p1 + (size_t)n * 16 * 576, lds, 16, 576, 24, 24, -1, 26, tid, 192, false);
    if (tid < 144) {
        int py = tid / 12, px = tid % 12;
        float bv = b[co];
        float s[2][2] = {{bv, bv}, {bv, bv}};
        for (int ci = 0; ci < 16; ++ci) {
            const float* chp = lds + ci * 728;
            float c[4][6];
            #pragma unroll
            for (int rr = 0; rr < 4; ++rr) {
                const float2* pr = (const float2*)(chp + (2 * py + rr) * 28);
                #pragma unroll
                for (int k = 0; k < 3; ++k) { float2 t = pr[px + k]; c[rr][2 * k] = t.x; c[rr][2 * k + 1] = t.y; }
            }
            LOAD_W9(wl, ci)
            #pragma unroll
            for (int dy = 0; dy < 3; ++dy)
                #pragma unroll
                for (int dx = 0; dx < 3; ++dx) {
                    float wv = w9[dy * 3 + dx];
                    #pragma unroll
                    for (int yy = 0; yy < 2; ++yy)
                        #pragma unroll
                        for (int xx = 0; xx < 2; ++xx)
                            s[yy][xx] = fmaf(c[yy + dy][xx + dx + 1], wv, s[yy][xx]);
                }
        }
        float* ob = e2 + (size_t)(n * 32 + co) * 576;
        float mx = -INFINITY;
        #pragma unroll
        for (int yy = 0; yy < 2; ++yy)
            #pragma unroll
            for (int xx = 0; xx < 2; ++xx) {
                float v = fmaxf(s[yy][xx], 0.f);
                ob[(2 * py + yy) * 24 + 2 * px + xx] = v;
                mx = fmaxf(mx, v);
            }
        p2[(size_t)(n * 32 + co) * 144 + py * 12 + px] = mx;
    }
}

// ---- bottleneck: conv3x3(Cin=32 @12)+relu -> bt. grid 128 ----
__global__ __launch_bounds__(192) void k_bott(const float* __restrict__ p2, const float* __restrict__ w,
                                              const float* __restrict__ b, float* __restrict__ bt) {
    int co = blockIdx.x & 63, n = blockIdx.x >> 6;
    int tid = threadIdx.x;
    __shared__ __align__(16) float lds[32 * 14 * 16];
    __shared__ __align__(16) float wl[384];
    for (int i = tid; i < 288; i += 192) wl[(i / 9) * 12 + (i % 9)] = w[(co * 32) * 9 + i];
    stage_rows(p2 + (size_t)n * 32 * 144, lds, 32, 144, 12, 12, -1, 14, tid, 192, false);
    if (tid < 144) {
        int y = tid / 12, x = tid % 12;
        float acc = b[co];
        for (int ci = 0; ci < 32; ++ci) {
            const float* chp = lds + ci * 224;
            LOAD_W9(wl, ci)
            #pragma unroll
            for (int dy = 0; dy < 3; ++dy)
                #pragma unroll
                for (int dx = 0; dx < 3; ++dx)
                    acc = fmaf(chp[(y + dy) * 16 + x + dx + 1], w9[dy * 3 + dx], acc);
        }
        bt[(size_t)(n * 64 + co) * 144 + y * 12 + x] = fmaxf(acc, 0.f);
    }
}

// ---- dec2 partial: conv3x3 over concat(up(bt)[64], e2[32]); ci-chunked, atomicAdd ----
__global__ __launch_bounds__(192) void k_dec2p(const float* __restrict__ bt, const float* __restrict__ e2,
                                               const float* __restrict__ w, float* __restrict__ d2b) {
    int bx = blockIdx.x;
    int chunk = bx & 3, co = (bx >> 2) & 31, n = bx >> 7;
    int cib = chunk * 24;
    int nA = max(0, min(24, 64 - cib));
    int nB = 24 - nA;
    int tid = threadIdx.x;
    __shared__ __align__(16) float lds[24 * 26 * 28];
    __shared__ __align__(16) float wl[288];
    for (int i = tid; i < 216; i += 192) wl[(i / 9) * 12 + (i % 9)] = w[((size_t)co * 96 + cib) * 9 + i];
    stage_rows(bt + ((size_t)n * 64 + cib) * 144, lds, nA, 144, 12, 12, -1, 14, tid, 192, false);
    float* ldsB = lds + nA * 224;
    int e2c = max(0, cib + nA - 64);
    stage_rows(e2 + ((size_t)n * 32 + e2c) * 576, ldsB, nB, 576, 24, 24, -1, 26, tid, 192, false);
    if (tid < 144) {
        int y = tid / 6, qx = tid % 6;
        float acc[4] = {0.f, 0.f, 0.f, 0.f};
        int r0 = ((y - 1) >> 1) + 1;
        int yodd = y & 1;
        for (int ci = 0; ci < nA; ++ci) {
            const float* chp = lds + ci * 224;
            const float2* p0 = (const float2*)(chp + r0 * 16);
            const float2* p1 = (const float2*)(chp + (r0 + 1) * 16);
            float a0[6], a1[6], am[6];
            #pragma unroll
            for (int k = 0; k < 3; ++k) {
                float2 t0 = p0[qx + k], t1 = p1[qx + k];
                a0[2 * k] = t0.x; a0[2 * k + 1] = t0.y;
                a1[2 * k] = t1.x; a1[2 * k + 1] = t1.y;
            }
            #pragma unroll
            for (int k = 0; k < 6; ++k) am[k] = yodd ? a0[k] : a1[k];
            LOAD_W9(wl, ci)
            #pragma unroll
            for (int dy = 0; dy < 3; ++dy) {
                const float* rr = (dy == 0) ? a0 : (dy == 1 ? am : a1);
                #pragma unroll
                for (int dx = 0; dx < 3; ++dx) {
                    float wv = w9[dy * 3 + dx];
                    #pragma unroll
                    for (int j = 0; j < 4; ++j)
                        acc[j] = fmaf(rr[((j + dx - 1) >> 1) + 2], wv, acc[j]);
                }
            }
        }
        for (int ci = 0; ci < nB; ++ci) {
            const float* chp = ldsB + ci * 728;
            float bvv[3][8];
            #pragma unroll
            for (int r = 0; r < 3; ++r) {
                const float2* pr = (const float2*)(chp + (y + r) * 28);
                #pragma unroll
                for (int k = 0; k < 4; ++k) { float2 t = pr[2 * qx + k]; bvv[r][2 * k] = t.x; bvv[r][2 * k + 1] = t.y; }
            }
            LOAD_W9(wl, nA + ci)
            #pragma unroll
            for (int dy = 0; dy < 3; ++dy)
                #pragma unroll
                for (int dx = 0; dx < 3; ++dx) {
                    float wv = w9[dy * 3 + dx];
                    #pragma unroll
                    for (int j = 0; j < 4; ++j)
                        acc[j] = fmaf(bvv[dy][j + dx + 1], wv, acc[j]);
                }
        }
        float* op = d2b + ((size_t)(n * 32 + co)) * 576 + y * 24 + qx * 4;
        #pragma unroll
        for (int j = 0; j < 4; ++j) atomicAdd(op + j, acc[j]);
    }
}

// ---- dec1 partial: conv3x3 over concat(up(relu(d2b))[32], e1u[16]); atomicAdd ----
__global__ __launch_bounds__(192) void k_dec1p(const float* __restrict__ d2b, const float* __restrict__ e1u,
                                               const float* __restrict__ w, float* __restrict__ d1b) {
    int bx = blockIdx.x;
    int strip = bx % 3;
    int chunk = (bx / 3) & 3;
    int co = (bx / 12) & 15;
    int n = bx / 192;
    int cib = chunk * 12;
    int nA = max(0, min(12, 32 - cib));
    int nB = 12 - nA;
    int y0 = strip * 16;
    int yhlo = (y0 - 1) >> 1;
    int tid = threadIdx.x;
    __shared__ __align__(16) float lds[12 * 18 * 52];
    __shared__ __align__(16) float wl[144];
    for (int i = tid; i < 108; i += 192) wl[(i / 9) * 12 + (i % 9)] = w[((size_t)co * 48 + cib) * 9 + i];
    stage_rows(d2b + ((size_t)n * 32 + cib) * 576, lds, nA, 576, 24, 24, yhlo, 10, tid, 192, true);
    float* ldsB = lds + nA * 280;
    int e1c = max(0, cib + nA - 32);
    stage_rows(e1u + ((size_t)n * 16 + e1c) * HW, ldsB, nB, HW, 48, 48, y0 - 1, 18, tid, 192, false);
    {
        int yl = tid / 12, qx = tid % 12;
        int y = y0 + yl;
        float acc[4] = {0.f, 0.f, 0.f, 0.f};
        int r0 = ((y - 1) >> 1) - yhlo;
        int yodd = y & 1;
        for (int ci = 0; ci < nA; ++ci) {
            const float* chp = lds + ci * 280;
            const float2* p0 = (const float2*)(chp + r0 * 28);
            const float2* p1 = (const float2*)(chp + (r0 + 1) * 28);
            float a0[6], a1[6], am[6];
            #pragma unroll
            for (int k = 0; k < 3; ++k) {
                float2 t0 = p0[qx + k], t1 = p1[qx + k];
                a0[2 * k] = t0.x; a0[2 * k + 1] = t0.y;
                a1[2 * k] = t1.x; a1[2 * k + 1] = t1.y;
            }
            #pragma unroll
            for (int k = 0; k < 6; ++k) am[k] = yodd ? a0[k] : a1[k];
            LOAD_W9(wl, ci)
            #pragma unroll
            for (int dy = 0; dy < 3; ++dy) {
                const float* rr = (dy == 0) ? a0 : (dy == 1 ? am : a1);
                #pragma unroll
                for (int dx = 0; dx < 3; ++dx) {
                    float wv = w9[dy * 3 + dx];
                    #pragma unroll
                    for (int j = 0; j < 4; ++j)
                        acc[j] = fmaf(rr[((j + dx - 1) >> 1) + 2], wv, acc[j]);
                }
            }
        }
        for (int ci = 0; ci < nB; ++ci) {
            const float* chp = ldsB + ci * 936;
            float bvv[3][8];
            #pragma unroll
            for (int r = 0; r < 3; ++r) {
                const float2* pr = (const float2*)(chp + (yl + r) * 52);
                #pragma unroll
                for (int k = 0; k < 4; ++k) { float2 t = pr[2 * qx + k]; bvv[r][2 * k] = t.x; bvv[r][2 * k + 1] = t.y; }
            }
            LOAD_W9(wl, nA + ci)
            #pragma unroll
            for (int dy = 0; dy < 3; ++dy)
                #pragma unroll
                for (int dx = 0; dx < 3; ++dx) {
                    float wv = w9[dy * 3 + dx];
                    #pragma unroll
                    for (int j = 0; j < 4; ++j)
                        acc[j] = fmaf(bvv[dy][j + dx + 1], wv, acc[j]);
                }
        }
        float* op = d1b + ((size_t)(n * 16 + co)) * HW + y * 48 + qx * 4;
        #pragma unroll
        for (int j = 0; j < 4; ++j) atomicAdd(op + j, acc[j]);
    }
}

// ---- out 1x1 conv over relu(d1b) -> x3s ----
__global__ void k_out1x1(const float* __restrict__ d1b, const float* __restrict__ ow,
                         const float* __restrict__ ob, float* __restrict__ x3s) {
    int idx = blockIdx.x * THREADS + threadIdx.x;
    if (idx >= 18432) return;
    int q = idx % HW;
    int co = (idx / HW) & 3;
    int n = idx / 9216;
    float acc = ob[co];
    #pragma unroll
    for (int ci = 0; ci < 16; ++ci)
        acc = fmaf(fmaxf(d1b[((size_t)(n * 16 + ci)) * HW + q], 0.f), ow[co * 16 + ci], acc);
    x3s[((size_t)(n * 4 + co)) * HW + q] = acc;
}

// ---- embedding for the current frame (arr=2, needs x3s) ----
__global__ __launch_bounds__(256) void k_emb3(const float* __restrict__ x3s,
                                              const float* __restrict__ ew, const float* __restrict__ eb,
                                              unsigned short* __restrict__ hl, float* __restrict__ nrm) {
    __shared__ float wl[1300];
    int ni = blockIdx.x / 9, pt = blockIdx.x % 9;
    int plane = 2 + (ni & 1) + 4 * (ni >> 1);
    emb_body(x3s + (size_t)plane * HW, 2, ni, pt, ew, eb, hl, nrm, wl, threadIdx.x, 256);
}

// ================= global matching via split-bf16 MFMA, pipelined =================
// 432 blocks = 8 (m,n) x 18 qt x 3 ps; XCD-chunk swizzle: each XCD owns one (m,n).
// block: 4 waves, 128 q rows; P chunk 768 = 24 sub-chunks of 32, double-buffered LDS.
#define NPC 24
__global__ __launch_bounds__(256, 2) void k_match(
        const unsigned short* __restrict__ hl, const float* __restrict__ nrm,
        unsigned* __restrict__ gmd, unsigned* __restrict__ lmd) {
    int bx = blockIdx.x;
    int l = (bx & 7) * 54 + (bx >> 3);        // bijective: 432 = 8*54
    int ps = l % 3;
    int qt = (l / 3) % 18;
    int mn = l / 54;
    int n = mn & 3;
    int m = mn >> 2;

    const unsigned short* curhl = hl + ((size_t)(8 + n)) * HW * 256;
    const unsigned short* refhl = hl + ((size_t)(m * 4 + n)) * HW * 256;
    const float* na = nrm + (size_t)(m * 4 + n) * HW;
    const float* nb = nrm + (size_t)(8 + n) * HW;
    unsigned* outd = (m == 0 ? gmd : lmd) + (size_t)n * HW;

    int qbase = qt * 128;
    int pbase = ps * 768;

    __shared__ __align__(16) unsigned short refl[2][32 * 256];   // 2 x 16 KB
    __shared__ __align__(16) float nal[768];                     // 3 KB

    int tid = threadIdx.x;
    int wave = tid >> 6;
    int lane = tid & 63;
    int lr = lane >> 5;
    int lc = lane & 31;

    // stage na chunk into LDS
    if (tid < 192) *(float4*)&nal[tid * 4] = *(const float4*)(na + pbase + tid * 4);

    // a-frags direct from global (linear layout)
    short8 ahi[2][4], alo[2][4];
    #pragma unroll
    for (int j = 0; j < 2; ++j) {
        int r = qbase + wave * 32 + j * 16 + (lane & 15);
        const unsigned short* rp = curhl + (size_t)r * 256;
        #pragma unroll
        for (int ks = 0; ks < 4; ++ks) {
            const unsigned short* p = rp + (ks * 4 + (lane >> 4)) * 8;
            ahi[j][ks] = *(const short8*)p;
            alo[j][ks] = *(const short8*)(p + 128);
        }
    }

    // prologue: stage chunk 0 into buf 0 (swizzled source, linear dest)
    {
        const unsigned short* gb = refhl + (size_t)pbase * 256;
        #pragma unroll
        for (int t = 0; t < 4; ++t) {
            int i = wave * 4 + t;
            int r = 2 * i + lr;
            gll16(gb + (size_t)r * 256 + (lc ^ (r & 7)) * 8, &refl[0][i * 512]);
        }
    }
    asm volatile("s_waitcnt lgkmcnt(0)" ::: "memory");   // nal writes visible before barrier

    float dmin[2][4];
    #pragma unroll
    for (int j = 0; j < 2; ++j)
        #pragma unroll
        for (int r = 0; r < 4; ++r) dmin[j][r] = INFINITY;

    for (int pc = 0; pc < NPC; ++pc) {
        int cur = pc & 1;
        if (pc + 1 < NPC) {    // stage next chunk into other buffer
            const unsigned short* gb = refhl + (size_t)(pbase + (pc + 1) * 32) * 256;
            #pragma unroll
            for (int t = 0; t < 4; ++t) {
                int i = wave * 4 + t;
                int r = 2 * i + lr;
                gll16(gb + (size_t)r * 256 + (lc ^ (r & 7)) * 8, &refl[cur ^ 1][i * 512]);
            }
            asm volatile("s_waitcnt vmcnt(4)" ::: "memory");   // current chunk landed; next in flight
        } else {
            asm volatile("s_waitcnt vmcnt(0)" ::: "memory");
        }
        __builtin_amdgcn_s_barrier();

        short8 bhi[2][4], blo[2][4];
        #pragma unroll
        for (int ptile = 0; ptile < 2; ++ptile) {
            int r = ptile * 16 + (lane & 15);
            #pragma unroll
            for (int ks = 0; ks < 4; ++ks) {
                int cg = ks * 4 + (lane >> 4);
                const char* p = (const char*)refl[cur] + r * 512 + ((cg ^ (r & 7)) << 4);
                bhi[ptile][ks] = *(const short8*)p;
                blo[ptile][ks] = *(const short8*)(p + 256);
            }
        }

        f32x4 acc[2][2];
        #pragma unroll
        for (int ptile = 0; ptile < 2; ++ptile)
            #pragma unroll
            for (int j = 0; j < 2; ++j) acc[ptile][j] = (f32x4){0.f, 0.f, 0.f, 0.f};

        #pragma unroll
        for (int ks = 0; ks < 4; ++ks) {
            #pragma unroll
            for (int ptile = 0; ptile < 2; ++ptile)
                #pragma unroll
                for (int j = 0; j < 2; ++j)
                    acc[ptile][j] = __builtin_amdgcn_mfma_f32_16x16x32_bf16(
                        ahi[j][ks], bhi[ptile][ks], acc[ptile][j], 0, 0, 0);
            #pragma unroll
            for (int ptile = 0; ptile < 2; ++ptile)
                #pragma unroll
                for (int j = 0; j < 2; ++j)
                    acc[ptile][j] = __builtin_amdgcn_mfma_f32_16x16x32_bf16(
                        ahi[j][ks], blo[ptile][ks], acc[ptile][j], 0, 0, 0);
            #pragma unroll
            for (int ptile = 0; ptile < 2; ++ptile)
                #pragma unroll
                for (int j = 0; j < 2; ++j)
                    acc[ptile][j] = __builtin_amdgcn_mfma_f32_16x16x32_bf16(
                        alo[j][ks], bhi[ptile][ks], acc[ptile][j], 0, 0, 0);
        }

        #pragma unroll
        for (int ptile = 0; ptile < 2; ++ptile) {
            float nav = nal[pc * 32 + ptile * 16 + (lane & 15)];
            #pragma unroll
            for (int j = 0; j < 2; ++j)
                #pragma unroll
                for (int r = 0; r < 4; ++r)
                    dmin[j][r] = fminf(dmin[j][r], fmaf(-2.f, acc[ptile][j][r], nav));
        }
        __builtin_amdgcn_s_barrier();   // all reads of refl[cur] done before it is restaged
    }

    #pragma unroll
    for (int j = 0; j < 2; ++j)
        #pragma unroll
        for (int r = 0; r < 4; ++r) {
            float v = dmin[j][r];
            v = fminf(v, __shfl_xor(v, 1, 64));
            v = fminf(v, __shfl_xor(v, 2, 64));
            v = fminf(v, __shfl_xor(v, 4, 64));
            v = fminf(v, __shfl_xor(v, 8, 64));
            if ((lane & 15) == 0) {
                int q = qbase + wave * 32 + j * 16 + 4 * (lane >> 4) + r;
                float d2 = fmaxf(v + nb[q], 0.f);
                atomicMin(&outd[q], __float_as_uint(d2));
            }
        }
}

// ============ final dsh conv (with inline distance->value map) ============
__global__ void k_final(const float* __restrict__ x3s, const unsigned* __restrict__ gmd,
                        const unsigned* __restrict__ lmd, const float* __restrict__ x2,
                        const float* __restrict__ dshw, const float* __restrict__ dshb,
                        float* __restrict__ out) {
    int idx = blockIdx.x * THREADS + threadIdx.x;
    if (idx >= 9216) return;
    int q = idx % HW, ni = idx / HW;
    int n = 2 + (ni & 1) + 4 * (ni >> 1);
    int b = ni >> 1;
    int x = q % 48, y = q / 48;
    float acc = dshb[0];
    for (int c = 0; c < 7; ++c) {
        const float* wp = dshw + c * 9;
        #pragma unroll
        for (int ky = 0; ky < 3; ++ky) {
            int yy = y + ky - 1;
            if (yy < 0 || yy >= 48) continue;
            #pragma unroll
            for (int kx = 0; kx < 3; ++kx) {
                int xx = x + kx - 1;
                if (xx < 0 || xx >= 48) continue;
                float v;
                if (c < 4) v = x3s[(size_t)(b * 4 + c) * HW + yy * 48 + xx];
                else if (c == 4) {
                    float d2 = __uint_as_float(gmd[(size_t)ni * HW + yy * 48 + xx]);
                    v = 1.f - 2.f / (1.f + expf(d2));
                } else if (c == 5) {
                    float d2 = __uint_as_float(lmd[(size_t)ni * HW + yy * 48 + xx]);
                    v = 1.f - 2.f / (1.f + expf(d2));
                } else v = x2[(size_t)n * HW + yy * 48 + xx];
                acc = fmaf(v, wp[ky * 3 + kx], acc);
            }
        }
    }
    out[idx] = acc;
}

extern "C" void kernel_launch(void* const* d_in, const int* in_sizes, int n_in,
                              void* d_out, int out_size, void* d_ws, size_t ws_size,
                              hipStream_t stream) {
    const float* x1     = (const float*)d_in[0];
    const float* x2     = (const float*)d_in[1];
    const float* x3     = (const float*)d_in[2];
    const float* enc1_w = (const float*)d_in[3];
    const float* enc1_b = (const float*)d_in[4];
    const float* enc2_w = (const float*)d_in[5];
    const float* enc2_b = (const float*)d_in[6];
    const float* bott_w = (const float*)d_in[7];
    const float* bott_b = (const float*)d_in[8];
    const float* dec2_w = (const float*)d_in[9];
    const float* dec2_b = (const float*)d_in[10];
    const float* dec1_w = (const float*)d_in[11];
    const float* dec1_b = (const float*)d_in[12];
    const float* out_w  = (const float*)d_in[13];
    const float* out_b  = (const float*)d_in[14];
    const float* emb_w  = (const float*)d_in[15];
    const float* emb_b  = (const float*)d_in[16];
    const float* dsh_w  = (const float*)d_in[17];
    const float* dsh_b  = (const float*)d_in[18];

    float* w = (float*)d_ws;
    float* e1u  = w;                   // 73728
    float* p1   = w + 73728;           // 18432
    float* e2   = w + 92160;           // 36864
    float* p2   = w + 129024;          // 9216
    float* bt   = w + 138240;          // 18432
    float* d2b  = w + 156672;          // 36864
    float* d1b  = w + 193536;          // 73728 (ends 267264)
    float* x3s  = w + 267264;          // 18432
    float* nrm  = w + 285696;          // 27648
    unsigned* gmd = (unsigned*)(w + 313344);   // 9216
    unsigned* lmd = (unsigned*)(w + 322560);   // 9216 (contiguous after gmd)
    unsigned short* hl = (unsigned short*)(w + 331776);  // 3*4*2304*256 ushorts

    k_pre<<<dim3(608), dim3(256), 0, stream>>>(d2b, d1b, dec2_b, dec1_b, x1, x2, emb_w, emb_b,
                                               hl, nrm, gmd, x3, enc1_w, enc1_b, e1u, p1);
    k_enc2pool<<<dim3(64), dim3(192), 0, stream>>>(p1, enc2_w, enc2_b, e2, p2);
    k_bott<<<dim3(128), dim3(192), 0, stream>>>(p2, bott_w, bott_b, bt);
    k_dec2p<<<dim3(256), dim3(192), 0, stream>>>(bt, e2, dec2_w, d2b);
    k_dec1p<<<dim3(384), dim3(192), 0, stream>>>(d2b, e1u, dec1_w, d1b);
    k_out1x1<<<dim3(72), dim3(THREADS), 0, stream>>>(d1b, out_w, out_b, x3s);
    k_emb3<<<dim3(36), dim3(256), 0, stream>>>(x3s, emb_w, emb_b, hl, nrm);
    k_match<<<dim3(432), dim3(256), 0, stream>>>(hl, nrm, gmd, lmd);
    k_final<<<dim3(36), dim3(THREADS), 0, stream>>>(x3s, gmd, lmd, x2, dsh_w, dsh_b, (float*)d_out);
}